// Round 3
// baseline (213.117 us; speedup 1.0000x reference)
//
#include <hip/hip_runtime.h>
#include <math.h>

#define NSAMP   32768
#define NFRAMES 128
#define NHARM   16
#define BATCH   64
#define MFFT    16384   // complex FFT size for the even/odd real pack (NSAMP/2)

static __device__ __forceinline__ float clampf(float x, float lo, float hi) {
  return fminf(fmaxf(x, lo), hi);
}

// ---------------------------------------------------------------------------
// K1: per-batch gumbel argmax -> f0 -> per-harmonic radians r (f64),
//     plus the sequential 128-frame envelope scan (f32, stable recursion).
// ---------------------------------------------------------------------------
__global__ __launch_bounds__(128) void k1_setup(
    const float* __restrict__ packed, const float* __restrict__ gumbel,
    double* __restrict__ r64_ws, float* __restrict__ env_ws) {
  __shared__ double zv[128];
  __shared__ int    zi[128];
  __shared__ double f0_sh;
  int b = blockIdx.x, tid = threadIdx.x;
  const float* pk = packed + b * 480;

  // z = logits + gumbel noise (f64 to track the stable reference)
  double u = (double)gumbel[b * 128 + tid];
  double t = -log(u + 1e-10);
  double g = -log(t + 1e-10);
  zv[tid] = (double)pk[tid] + g;
  zi[tid] = tid;
  __syncthreads();
  for (int s = 64; s > 0; s >>= 1) {           // argmax, first-index tiebreak
    if (tid < s) {
      double a = zv[tid], c = zv[tid + s];
      int ia = zi[tid], ic = zi[tid + s];
      if (c > a || (c == a && ic < ia)) { zv[tid] = c; zi[tid] = ic; }
    }
    __syncthreads();
  }
  if (tid == 0) {
    int note = zi[0];
    // FREQS is explicitly float32 in the reference -> round through f32
    double Fd  = 440.0 * exp2(((double)(note - 69)) / 12.0) / 11025.0;
    float  F32 = (float)Fd;
    double f0  = (double)F32 * 11025.0;
    f0 = (40.0 / 11025.0) + f0 * (3000.0 / 11025.0 - 40.0 / 11025.0);
    f0_sh = f0;
  }
  __syncthreads();
  if (tid < NHARM) {
    int h = tid;
    int c = b * NHARM + h;
    const float  PIF = 3.14159265358979323846f;     // float32(np.pi)
    double osc = f0_sh * (double)(h + 1);
    r64_ws[c] = (osc / 11025.0) * (double)PIF;
    // envelope scan: cur = clip(cur + a*ha, 0,1); emit; cur *= hd
    float ha = pk[384 + h];
    float hd = 0.1f + pk[400 + h] * 0.9f;
    float cur = 0.0f;
    for (int tt = 0; tt < NFRAMES; ++tt) {
      float a = pk[256 + tt] * 2.0f - 1.0f;
      cur = clampf(cur + a * ha, 0.0f, 1.0f);
      env_ws[c * NFRAMES + tt] = cur;
      cur = cur * hd;
    }
  }
}

// ---------------------------------------------------------------------------
// K3: oscillator bank + env lerp + mean-reduce.
// phase(s) = (s+1)*r  (mod 2pi), f64 chunk-reduced; sinf on small argument.
// grid = (4 channel-groups of 256, 128 chunks of 256 samples)
// ---------------------------------------------------------------------------
__global__ __launch_bounds__(256) void k3_osc(
    const double* __restrict__ r64_ws, const float* __restrict__ env_ws,
    float* __restrict__ out) {
  const double TWO_PI = 6.283185307179586;
  int tid = threadIdx.x;
  int c = blockIdx.x * 256 + tid;     // channel = b*16 + h
  int k = blockIdx.y;                 // sample chunk, 256 samples
  double r  = r64_ws[c];
  double rr = fmod(r, TWO_PI);
  int s0 = k * 256;
  double ph = fmod((double)s0 * r, TWO_PI);
  // env frames touched by this chunk: {k-1, k, k+1} (clamped)
  int km1 = (k > 0) ? (k - 1) : 0;
  int kp1 = (k < 127) ? (k + 1) : 127;
  float ea = env_ws[c * NFRAMES + km1];
  float eb = env_ws[c * NFRAMES + k];
  float ec = env_ws[c * NFRAMES + kp1];
  for (int i = 0; i < 256; ++i) {
    int s = s0 + i;
    ph += rr;                          // f64: keeps reduced phase exact enough
    float coords = ((float)s + 0.5f) * (1.0f / 256.0f) - 0.5f;  // exact in f32
    coords = clampf(coords, 0.0f, 127.0f);
    int i0 = (int)coords;
    float w = coords - (float)i0;
    float e0 = (i0 < k) ? ea : eb;
    float e1 = (i0 < k) ? eb : ec;
    float ev = e0 * (1.0f - w) + e1 * w;
    float val = ev * sinf((float)ph);
    #pragma unroll
    for (int off = 32; off > 0; off >>= 1)
      val += __shfl_xor(val, off, 64);       // sum 64 channels (one wave)
    if ((tid & 63) == 0)
      atomicAdd(&out[s], val * (1.0f / 1024.0f));
  }
}

// ---------------------------------------------------------------------------
// K_noise: per-batch  irfft( rfft(2u-1) * H ) * clip(amp_full,0,1) / 64
// via a 16384-pt complex LDS FFT with the real even/odd pack.
// H = lerp(noise_filter -> 16384), H[16384] = 0 (the reference's pad);
// the 1/M inverse scale is folded into H.
// ---------------------------------------------------------------------------
static __device__ __forceinline__ float h_filter(int f, const float* nf_s) {
  if (f >= MFFT) return 0.0f;                       // padded bin
  float coords = ((float)f + 0.5f) * (1.0f / 256.0f) - 0.5f;
  coords = clampf(coords, 0.0f, 63.0f);
  int i0 = (int)coords;
  int i1 = (i0 < 63) ? (i0 + 1) : 63;
  float w = coords - (float)i0;
  return nf_s[i0] * (1.0f - w) + nf_s[i1] * w;
}

static __device__ __forceinline__ float amp_lerp(int s, const float* amp_s) {
  float coords = ((float)s + 0.5f) * (1.0f / 256.0f) - 0.5f;
  coords = clampf(coords, 0.0f, 127.0f);
  int i0 = (int)coords;
  int i1 = (i0 < 127) ? (i0 + 1) : 127;
  float w = coords - (float)i0;
  float v = amp_s[i0] * (1.0f - w) + amp_s[i1] * w;
  return clampf(v, 0.0f, 1.0f);
}

__global__ __launch_bounds__(256) void k_noise(
    const float* __restrict__ packed, const float* __restrict__ noise_u,
    float* __restrict__ out) {
  __shared__ float2 zs[MFFT];        // 128 KiB
  __shared__ float  nf_s[64];
  __shared__ float  amp_s[128];
  int b = blockIdx.x, tid = threadIdx.x;
  const float* pk = packed + b * 480;
  if (tid < 64)  nf_s[tid]  = pk[416 + tid];
  if (tid < 128) amp_s[tid] = pk[256 + tid] * 2.0f - 1.0f;

  // bit-reversed load of the packed complex signal z[n] = x[2n] + i x[2n+1]
  const float* nu = noise_u + b * NSAMP;
  for (int n = tid; n < MFFT; n += 256) {
    float x0 = nu[2 * n]     * 2.0f - 1.0f;
    float x1 = nu[2 * n + 1] * 2.0f - 1.0f;
    int j = __brev((unsigned)n) >> 18;       // bitrev14
    zs[j] = make_float2(x0, x1);
  }
  __syncthreads();

  // forward DIT (bitrev input -> natural output), W = e^{-i pi k/half}
  for (int half = 1; half < MFFT; half <<= 1) {
    float mult = -(float)M_PI / (float)half;
    for (int i = tid; i < MFFT / 2; i += 256) {
      int kk = i & (half - 1);
      int p0 = ((i & ~(half - 1)) << 1) | kk;
      int p1 = p0 + half;
      float ss, cc; __sincosf(mult * (float)kk, &ss, &cc);
      float2 a = zs[p0], bv = zs[p1];
      float2 t = make_float2(cc * bv.x - ss * bv.y, cc * bv.y + ss * bv.x);
      zs[p0] = make_float2(a.x + t.x, a.y + t.y);
      zs[p1] = make_float2(a.x - t.x, a.y - t.y);
    }
    __syncthreads();
  }

  // Hermitian unpack -> multiply by H/M -> repack for the inverse transform
  const float hsc = 1.0f / (float)MFFT;
  for (int f = tid; f <= MFFT / 2; f += 256) {
    if (f == 0) {
      float2 Z0 = zs[0];
      float X0 = Z0.x + Z0.y;                 // X[0]
      float Y0 = X0 * (h_filter(0, nf_s) * hsc);
      // X[M] pairs with H[M] = 0  =>  YM = 0
      zs[0] = make_float2(0.5f * Y0, 0.5f * Y0);
    } else if (f == MFFT / 2) {
      // X[M/2] = conj(Z[M/2]);  Z2[M/2] = conj(Y) = Z[M/2]*H
      float Hm = h_filter(MFFT / 2, nf_s) * hsc;
      float2 Zm = zs[MFFT / 2];
      zs[MFFT / 2] = make_float2(Zm.x * Hm, Zm.y * Hm);
    } else {
      int gi = MFFT - f;
      float2 Zf = zs[f], Zg = zs[gi];
      float Ax = 0.5f * (Zf.x + Zg.x), Ay = 0.5f * (Zf.y - Zg.y);
      float Bx = 0.5f * (Zf.x - Zg.x), By = 0.5f * (Zf.y + Zg.y);
      float ang = (-(float)M_PI / (float)MFFT) * (float)f;  // W = e^{-i pi f/M}
      float ss, cc; __sincosf(ang, &ss, &cc);
      float WBx = cc * Bx - ss * By, WBy = cc * By + ss * Bx;
      // X[f] = A - i W B ; X[M-f] = conj(A) - i conj(WB)
      float Hf = h_filter(f,  nf_s) * hsc;
      float Hg = h_filter(gi, nf_s) * hsc;
      float Yfx = (Ax + WBy) * Hf, Yfy = (Ay - WBx) * Hf;
      float Ygx = (Ax - WBy) * Hg, Ygy = (-Ay - WBx) * Hg;
      float A2x = 0.5f * (Yfx + Ygx), A2y = 0.5f * (Yfy - Ygy);
      float B2x = 0.5f * (Yfx - Ygx), B2y = 0.5f * (Yfy + Ygy);
      // Z2[f]   = A2 + i*(conj(W)*B2)
      float CBx = cc * B2x + ss * B2y;
      float CBy = cc * B2y - ss * B2x;
      zs[f] = make_float2(A2x - CBy, A2y + CBx);
      // Z2[M-f] = conj(A2) + i*(W*conj(B2))
      float DBx = cc * B2x + ss * B2y;   // re(W*conj(B2))
      float DBy = ss * B2x - cc * B2y;   // im(W*conj(B2))
      zs[gi] = make_float2(A2x - DBy, -A2y + DBx);
    }
  }
  __syncthreads();

  // inverse DIF (natural input -> bitrev output), W = e^{+i pi k/half}
  for (int half = MFFT / 2; half >= 1; half >>= 1) {
    float mult = (float)M_PI / (float)half;
    for (int i = tid; i < MFFT / 2; i += 256) {
      int kk = i & (half - 1);
      int p0 = ((i & ~(half - 1)) << 1) | kk;
      int p1 = p0 + half;
      float ss, cc; __sincosf(mult * (float)kk, &ss, &cc);
      float2 u = zs[p0], v = zs[p1];
      zs[p0] = make_float2(u.x + v.x, u.y + v.y);
      float dx = u.x - v.x, dy = u.y - v.y;
      zs[p1] = make_float2(cc * dx - ss * dy, cc * dy + ss * dx);
    }
    __syncthreads();
  }

  // un-bit-reverse at the store; y[2n], y[2n+1] from the packed result
  for (int n = tid; n < MFFT; n += 256) {
    int j = __brev((unsigned)n) >> 18;
    float2 y = zs[j];
    int s0 = 2 * n, s1 = 2 * n + 1;
    atomicAdd(&out[s0], y.x * amp_lerp(s0, amp_s) * (1.0f / 64.0f));
    atomicAdd(&out[s1], y.y * amp_lerp(s1, amp_s) * (1.0f / 64.0f));
  }
}

// ---------------------------------------------------------------------------
extern "C" void kernel_launch(void* const* d_in, const int* in_sizes, int n_in,
                              void* d_out, int out_size, void* d_ws, size_t ws_size,
                              hipStream_t stream) {
  const float* packed  = (const float*)d_in[0];
  const float* gumbel  = (const float*)d_in[1];
  const float* noise_u = (const float*)d_in[2];
  float* out = (float*)d_out;

  // workspace carve: 1024 doubles (radians) + 1024*128 floats (env)
  double* r64_ws = (double*)d_ws;
  float*  env_ws = (float*)((char*)d_ws + 1024 * sizeof(double));

  hipMemsetAsync(d_out, 0, NSAMP * sizeof(float), stream);
  k1_setup<<<BATCH, 128, 0, stream>>>(packed, gumbel, r64_ws, env_ws);
  k3_osc<<<dim3(4, 128), 256, 0, stream>>>(r64_ws, env_ws, out);
  k_noise<<<BATCH, 256, 0, stream>>>(packed, noise_u, out);
}

// Round 4
// 126.979 us; speedup vs baseline: 1.6784x; 1.6784x over previous
//
#include <hip/hip_runtime.h>
#include <math.h>

#define NSAMP   32768
#define NFRAMES 128
#define NHARM   16
#define BATCH   64
#define MFFT    16384   // complex FFT size for the even/odd real pack (NSAMP/2)

// LDS physical index swizzle: pad every 16 and every 256 float2 entries.
// Makes radix-2 butterfly strides <=2-way (free) and the bit-reversed
// scatter (all indices multiples of 256) 4-way (= wave64 b64 floor).
#define ZPAD(p) ((p) + ((p) >> 4) + ((p) >> 8))
#define ZSIZE   (MFFT + (MFFT >> 4) + (MFFT >> 8))   // 17472 float2

static __device__ __forceinline__ float clampf(float x, float lo, float hi) {
  return fminf(fmaxf(x, lo), hi);
}

// ---------------------------------------------------------------------------
// K1: per-batch gumbel argmax -> f0 -> per-harmonic radians r (f64),
//     plus the sequential 128-frame envelope scan (f32, stable recursion).
// ---------------------------------------------------------------------------
__global__ __launch_bounds__(128) void k1_setup(
    const float* __restrict__ packed, const float* __restrict__ gumbel,
    double* __restrict__ r64_ws, float* __restrict__ env_ws) {
  __shared__ double zv[128];
  __shared__ int    zi[128];
  __shared__ double f0_sh;
  int b = blockIdx.x, tid = threadIdx.x;
  const float* pk = packed + b * 480;

  double u = (double)gumbel[b * 128 + tid];
  double t = -log(u + 1e-10);
  double g = -log(t + 1e-10);
  zv[tid] = (double)pk[tid] + g;
  zi[tid] = tid;
  __syncthreads();
  for (int s = 64; s > 0; s >>= 1) {           // argmax, first-index tiebreak
    if (tid < s) {
      double a = zv[tid], c = zv[tid + s];
      int ia = zi[tid], ic = zi[tid + s];
      if (c > a || (c == a && ic < ia)) { zv[tid] = c; zi[tid] = ic; }
    }
    __syncthreads();
  }
  if (tid == 0) {
    int note = zi[0];
    double Fd  = 440.0 * exp2(((double)(note - 69)) / 12.0) / 11025.0;
    float  F32 = (float)Fd;                     // FREQS is f32 in the reference
    double f0  = (double)F32 * 11025.0;
    f0 = (40.0 / 11025.0) + f0 * (3000.0 / 11025.0 - 40.0 / 11025.0);
    f0_sh = f0;
  }
  __syncthreads();
  if (tid < NHARM) {
    int h = tid;
    int c = b * NHARM + h;
    const float PIF = 3.14159265358979323846f;  // float32(np.pi)
    double osc = f0_sh * (double)(h + 1);
    r64_ws[c] = (osc / 11025.0) * (double)PIF;
    float ha = pk[384 + h];
    float hd = 0.1f + pk[400 + h] * 0.9f;
    float cur = 0.0f;
    for (int tt = 0; tt < NFRAMES; ++tt) {
      float a = pk[256 + tt] * 2.0f - 1.0f;
      cur = clampf(cur + a * ha, 0.0f, 1.0f);
      env_ws[c * NFRAMES + tt] = cur;
      cur = cur * hd;
    }
  }
}

// ---------------------------------------------------------------------------
// K3: oscillator bank + env lerp + mean-reduce.
// Phase re-anchored per 256-sample chunk in f64, advanced by f32 rotation
// (drift <= ~1e-4 rad per chunk). Env is piecewise-linear per chunk-half ->
// incremental adds. Cross-channel (64-lane) sum via 4-sample reduce-scatter.
// grid = (4 channel-groups of 256, 128 chunks of 256 samples)
// ---------------------------------------------------------------------------
__global__ __launch_bounds__(256) void k3_osc(
    const double* __restrict__ r64_ws, const float* __restrict__ env_ws,
    float* __restrict__ out) {
  const double TWO_PI     = 6.283185307179586476925286766559;
  const double INV_TWO_PI = 0.15915494309189533576888376337251;
  int tid  = threadIdx.x;
  int lane = tid & 63;
  int c = blockIdx.x * 256 + tid;     // channel = b*16 + h
  int k = blockIdx.y;                 // sample chunk of 256
  int s0 = k * 256;

  double r  = r64_ws[c];
  double rr = r - rint(r * INV_TWO_PI) * TWO_PI;            // step angle mod 2pi
  double x0 = (double)(s0 + 1) * r;                          // phase of sample s0
  double ph = x0 - rint(x0 * INV_TWO_PI) * TWO_PI;
  float sph, cph; __sincosf((float)ph, &sph, &cph);
  float srot, crot; __sincosf((float)rr, &srot, &crot);

  int km1 = (k > 0) ? (k - 1) : 0;
  int kp1 = (k < 127) ? (k + 1) : 127;
  float ea = env_ws[c * NFRAMES + km1];
  float eb = env_ws[c * NFRAMES + k];
  float ec = env_ws[c * NFRAMES + kp1];

  int sbase = s0;
  #pragma unroll
  for (int half = 0; half < 2; ++half) {
    float ev, slope;
    if (half == 0) { slope = (eb - ea) * (1.0f / 256.0f); ev = ea + (eb - ea) * (128.5f / 256.0f); }
    else           { slope = (ec - eb) * (1.0f / 256.0f); ev = eb + (ec - eb) * (0.5f / 256.0f); }
    for (int it = 0; it < 32; ++it) {
      float v0, v1, v2, v3, tn;
      v0 = ev * sph; tn = sph*crot + cph*srot; cph = cph*crot - sph*srot; sph = tn; ev += slope;
      v1 = ev * sph; tn = sph*crot + cph*srot; cph = cph*crot - sph*srot; sph = tn; ev += slope;
      v2 = ev * sph; tn = sph*crot + cph*srot; cph = cph*crot - sph*srot; sph = tn; ev += slope;
      v3 = ev * sph; tn = sph*crot + cph*srot; cph = cph*crot - sph*srot; sph = tn; ev += slope;
      // reduce-scatter across 64 lanes: 4 sample-sums land in lanes 0/16/32/48
      float t0 = __shfl_xor(v0, 32);
      float t1 = __shfl_xor(v1, 32);
      float t2 = __shfl_xor(v2, 32);
      float t3 = __shfl_xor(v3, 32);
      bool b5 = (lane & 32) != 0;
      float w0 = b5 ? (v2 + t2) : (v0 + t0);
      float w1 = b5 ? (v3 + t3) : (v1 + t1);
      t0 = __shfl_xor(w0, 16);
      t1 = __shfl_xor(w1, 16);
      float xs = (lane & 16) ? (w1 + t1) : (w0 + t0);
      xs += __shfl_xor(xs, 8);
      xs += __shfl_xor(xs, 4);
      xs += __shfl_xor(xs, 2);
      xs += __shfl_xor(xs, 1);
      if ((lane & 15) == 0)
        atomicAdd(&out[sbase + (lane >> 4)], xs * (1.0f / 1024.0f));
      sbase += 4;
    }
  }
}

// ---------------------------------------------------------------------------
// K_noise: per-batch  irfft( rfft(2u-1) * H ) * clip(amp_full,0,1) / 64
// 16384-pt complex LDS FFT (even/odd real pack). 1024 threads, padded LDS,
// loop-invariant / rotated twiddles.
// ---------------------------------------------------------------------------
static __device__ __forceinline__ float h_filter(int f, const float* nf_s) {
  if (f >= MFFT) return 0.0f;                       // padded bin
  float coords = ((float)f + 0.5f) * (1.0f / 256.0f) - 0.5f;
  coords = clampf(coords, 0.0f, 63.0f);
  int i0 = (int)coords;
  int i1 = (i0 < 63) ? (i0 + 1) : 63;
  float w = coords - (float)i0;
  return nf_s[i0] * (1.0f - w) + nf_s[i1] * w;
}

static __device__ __forceinline__ float amp_lerp(int s, const float* amp_s) {
  float coords = ((float)s + 0.5f) * (1.0f / 256.0f) - 0.5f;
  coords = clampf(coords, 0.0f, 127.0f);
  int i0 = (int)coords;
  int i1 = (i0 < 127) ? (i0 + 1) : 127;
  float w = coords - (float)i0;
  float v = amp_s[i0] * (1.0f - w) + amp_s[i1] * w;
  return clampf(v, 0.0f, 1.0f);
}

__global__ __launch_bounds__(1024) void k_noise(
    const float* __restrict__ packed, const float* __restrict__ noise_u,
    float* __restrict__ out) {
  __shared__ float2 zs[ZSIZE];        // ~136.5 KiB padded
  __shared__ float  nf_s[64];
  __shared__ float  amp_s[128];
  int b = blockIdx.x, tid = threadIdx.x;
  const float* pk = packed + b * 480;
  if (tid < 64)  nf_s[tid]  = pk[416 + tid];
  if (tid < 128) amp_s[tid] = pk[256 + tid] * 2.0f - 1.0f;

  // bit-reversed load of z[n] = x[2n] + i x[2n+1]
  const float2* nu2 = (const float2*)(noise_u + b * NSAMP);
  for (int n = tid; n < MFFT; n += 1024) {
    float2 xv = nu2[n];
    int j = __brev((unsigned)n) >> 18;       // bitrev14
    zs[ZPAD(j)] = make_float2(xv.x * 2.0f - 1.0f, xv.y * 2.0f - 1.0f);
  }
  __syncthreads();

  // forward DIT (bitrev -> natural), W = e^{-i pi k/half}
  for (int half = 1; half < MFFT; half <<= 1) {
    float mult = -(float)M_PI / (float)half;
    float sa = 0.0f, ca = 1.0f;
    if (half > 1024) __sincosf(mult * 1024.0f, &sa, &ca);
    float ss = 0.0f, cc = 1.0f;
    int kkprev = -100000;
    for (int i = tid; i < MFFT / 2; i += 1024) {
      int kk = i & (half - 1);
      if (kk == kkprev) {
        // twiddle unchanged
      } else if (kk == kkprev + 1024) {
        float tn = cc * ca - ss * sa; ss = ss * ca + cc * sa; cc = tn;
      } else {
        __sincosf(mult * (float)kk, &ss, &cc);
      }
      kkprev = kk;
      int p0 = ((i & ~(half - 1)) << 1) | kk;
      int p1 = p0 + half;
      float2 a = zs[ZPAD(p0)], bv = zs[ZPAD(p1)];
      float2 t = make_float2(cc * bv.x - ss * bv.y, cc * bv.y + ss * bv.x);
      zs[ZPAD(p0)] = make_float2(a.x + t.x, a.y + t.y);
      zs[ZPAD(p1)] = make_float2(a.x - t.x, a.y - t.y);
    }
    __syncthreads();
  }

  // Hermitian unpack -> multiply by H/M -> repack for the inverse transform
  const float hsc = 1.0f / (float)MFFT;
  for (int f = tid; f <= MFFT / 2; f += 1024) {
    if (f == 0) {
      float2 Z0 = zs[ZPAD(0)];
      float X0 = Z0.x + Z0.y;
      float Y0 = X0 * (h_filter(0, nf_s) * hsc);
      zs[ZPAD(0)] = make_float2(0.5f * Y0, 0.5f * Y0);   // H[M]=0 => YM=0
    } else if (f == MFFT / 2) {
      float Hm = h_filter(MFFT / 2, nf_s) * hsc;
      float2 Zm = zs[ZPAD(MFFT / 2)];
      zs[ZPAD(MFFT / 2)] = make_float2(Zm.x * Hm, Zm.y * Hm);
    } else {
      int gi = MFFT - f;
      float2 Zf = zs[ZPAD(f)], Zg = zs[ZPAD(gi)];
      float Ax = 0.5f * (Zf.x + Zg.x), Ay = 0.5f * (Zf.y - Zg.y);
      float Bx = 0.5f * (Zf.x - Zg.x), By = 0.5f * (Zf.y + Zg.y);
      float ang = (-(float)M_PI / (float)MFFT) * (float)f;
      float ss, cc; __sincosf(ang, &ss, &cc);
      float WBx = cc * Bx - ss * By, WBy = cc * By + ss * Bx;
      float Hf = h_filter(f,  nf_s) * hsc;
      float Hg = h_filter(gi, nf_s) * hsc;
      float Yfx = (Ax + WBy) * Hf, Yfy = (Ay - WBx) * Hf;
      float Ygx = (Ax - WBy) * Hg, Ygy = (-Ay - WBx) * Hg;
      float A2x = 0.5f * (Yfx + Ygx), A2y = 0.5f * (Yfy - Ygy);
      float B2x = 0.5f * (Yfx - Ygx), B2y = 0.5f * (Yfy + Ygy);
      float CBx = cc * B2x + ss * B2y;
      float CBy = cc * B2y - ss * B2x;
      zs[ZPAD(f)]  = make_float2(A2x - CBy, A2y + CBx);
      float DBx = cc * B2x + ss * B2y;
      float DBy = ss * B2x - cc * B2y;
      zs[ZPAD(gi)] = make_float2(A2x - DBy, -A2y + DBx);
    }
  }
  __syncthreads();

  // inverse DIF (natural -> bitrev), W = e^{+i pi k/half}
  for (int half = MFFT / 2; half >= 1; half >>= 1) {
    float mult = (float)M_PI / (float)half;
    float sa = 0.0f, ca = 1.0f;
    if (half > 1024) __sincosf(mult * 1024.0f, &sa, &ca);
    float ss = 0.0f, cc = 1.0f;
    int kkprev = -100000;
    for (int i = tid; i < MFFT / 2; i += 1024) {
      int kk = i & (half - 1);
      if (kk == kkprev) {
      } else if (kk == kkprev + 1024) {
        float tn = cc * ca - ss * sa; ss = ss * ca + cc * sa; cc = tn;
      } else {
        __sincosf(mult * (float)kk, &ss, &cc);
      }
      kkprev = kk;
      int p0 = ((i & ~(half - 1)) << 1) | kk;
      int p1 = p0 + half;
      float2 u = zs[ZPAD(p0)], v = zs[ZPAD(p1)];
      zs[ZPAD(p0)] = make_float2(u.x + v.x, u.y + v.y);
      float dx = u.x - v.x, dy = u.y - v.y;
      zs[ZPAD(p1)] = make_float2(cc * dx - ss * dy, cc * dy + ss * dx);
    }
    __syncthreads();
  }

  // un-bit-reverse at the store; y[2n], y[2n+1] from the packed result
  for (int n = tid; n < MFFT; n += 1024) {
    int j = __brev((unsigned)n) >> 18;
    float2 y = zs[ZPAD(j)];
    int s0 = 2 * n, s1 = 2 * n + 1;
    atomicAdd(&out[s0], y.x * amp_lerp(s0, amp_s) * (1.0f / 64.0f));
    atomicAdd(&out[s1], y.y * amp_lerp(s1, amp_s) * (1.0f / 64.0f));
  }
}

// ---------------------------------------------------------------------------
extern "C" void kernel_launch(void* const* d_in, const int* in_sizes, int n_in,
                              void* d_out, int out_size, void* d_ws, size_t ws_size,
                              hipStream_t stream) {
  const float* packed  = (const float*)d_in[0];
  const float* gumbel  = (const float*)d_in[1];
  const float* noise_u = (const float*)d_in[2];
  float* out = (float*)d_out;

  double* r64_ws = (double*)d_ws;
  float*  env_ws = (float*)((char*)d_ws + 1024 * sizeof(double));

  hipMemsetAsync(d_out, 0, NSAMP * sizeof(float), stream);
  k1_setup<<<BATCH, 128, 0, stream>>>(packed, gumbel, r64_ws, env_ws);
  k3_osc<<<dim3(4, 128), 256, 0, stream>>>(r64_ws, env_ws, out);
  k_noise<<<BATCH, 1024, 0, stream>>>(packed, noise_u, out);
}

// Round 5
// 95.425 us; speedup vs baseline: 2.2333x; 1.3307x over previous
//
#include <hip/hip_runtime.h>
#include <math.h>

#define NSAMP   32768
#define NFRAMES 128
#define NHARM   16
#define BATCH   64
#define MFFT    16384          // complex FFT size (even/odd real pack), = 128*128
#define ZROW    137            // LDS row stride (float2) for 128-entry FFT rows

static __device__ __forceinline__ float clampf(float x, float lo, float hi) {
  return fminf(fmaxf(x, lo), hi);
}
static __device__ __forceinline__ int zp(int fft, int p) {        // LDS swizzle
  return fft * ZROW + p + (p >> 4);
}
static __device__ __forceinline__ int brev7(int n) {
  return (int)(__brev((unsigned)n) >> 25);
}

// 7-stage radix-2 DIT over 32 FFTs of length 128 resident in LDS.
// Input must be loaded at bit-reversed positions; output is natural order.
// tws[j] = (cos(-pi j/64), sin(-pi j/64)); INV conjugates the twiddle.
template <bool INV>
static __device__ __forceinline__ void fft_stages(float2* zs, const float2* tws, int tid) {
  for (int s = 0; s < 7; ++s) {
    int half = 1 << s;
    for (int j = tid; j < 2048; j += 512) {
      int fft = j >> 6, bf = j & 63;
      int kk = bf & (half - 1);
      int p0 = ((bf & ~(half - 1)) << 1) | kk;
      int p1 = p0 + half;
      float2 w = tws[kk << (6 - s)];
      float cc = w.x, ss = INV ? -w.y : w.y;
      int a0 = zp(fft, p0), a1 = zp(fft, p1);
      float2 a = zs[a0], bv = zs[a1];
      float2 t = make_float2(cc * bv.x - ss * bv.y, cc * bv.y + ss * bv.x);
      zs[a0] = make_float2(a.x + t.x, a.y + t.y);
      zs[a1] = make_float2(a.x - t.x, a.y - t.y);
    }
    __syncthreads();
  }
}

static __device__ __forceinline__ void tw_init(float2* tws, int tid) {
  if (tid < 64) {
    float s, c;
    __sincosf(-(float)M_PI * (float)tid * (1.0f / 64.0f), &s, &c);
    tws[tid] = make_float2(c, s);
  }
}

static __device__ __forceinline__ float h_filter(int f, const float* nf_s) {
  float coords = ((float)f + 0.5f) * (1.0f / 256.0f) - 0.5f;
  coords = clampf(coords, 0.0f, 63.0f);
  int i0 = (int)coords;
  int i1 = (i0 < 63) ? (i0 + 1) : 63;
  float w = coords - (float)i0;
  return nf_s[i0] * (1.0f - w) + nf_s[i1] * w;
}

static __device__ __forceinline__ float amp_lerp(int s, const float* amp_s) {
  float coords = ((float)s + 0.5f) * (1.0f / 256.0f) - 0.5f;
  coords = clampf(coords, 0.0f, 127.0f);
  int i0 = (int)coords;
  int i1 = (i0 < 127) ? (i0 + 1) : 127;
  float w = coords - (float)i0;
  float v = amp_s[i0] * (1.0f - w) + amp_s[i1] * w;
  return clampf(v, 0.0f, 1.0f);
}

// ---------------------------------------------------------------------------
// K1: gumbel argmax -> f0 -> per-harmonic radians (f64); 128-frame env scan.
// env layout: env_ws[frame*1024 + channel]  (coalesced for k3)
// ---------------------------------------------------------------------------
__global__ __launch_bounds__(128) void k1_setup(
    const float* __restrict__ packed, const float* __restrict__ gumbel,
    double* __restrict__ r64_ws, float* __restrict__ env_ws) {
  __shared__ double zv[128];
  __shared__ int    zi[128];
  __shared__ double f0_sh;
  int b = blockIdx.x, tid = threadIdx.x;
  const float* pk = packed + b * 480;

  double u = (double)gumbel[b * 128 + tid];
  double t = -log(u + 1e-10);
  double g = -log(t + 1e-10);
  zv[tid] = (double)pk[tid] + g;
  zi[tid] = tid;
  __syncthreads();
  for (int s = 64; s > 0; s >>= 1) {
    if (tid < s) {
      double a = zv[tid], c = zv[tid + s];
      int ia = zi[tid], ic = zi[tid + s];
      if (c > a || (c == a && ic < ia)) { zv[tid] = c; zi[tid] = ic; }
    }
    __syncthreads();
  }
  if (tid == 0) {
    int note = zi[0];
    double Fd  = 440.0 * exp2(((double)(note - 69)) / 12.0) / 11025.0;
    float  F32 = (float)Fd;                     // FREQS is f32 in the reference
    double f0  = (double)F32 * 11025.0;
    f0 = (40.0 / 11025.0) + f0 * (3000.0 / 11025.0 - 40.0 / 11025.0);
    f0_sh = f0;
  }
  __syncthreads();
  if (tid < NHARM) {
    int h = tid;
    int c = b * NHARM + h;
    const float PIF = 3.14159265358979323846f;  // float32(np.pi)
    double osc = f0_sh * (double)(h + 1);
    r64_ws[c] = (osc / 11025.0) * (double)PIF;
    float ha = pk[384 + h];
    float hd = 0.1f + pk[400 + h] * 0.9f;
    float cur = 0.0f;
    for (int tt = 0; tt < NFRAMES; ++tt) {
      float a = pk[256 + tt] * 2.0f - 1.0f;
      cur = clampf(cur + a * ha, 0.0f, 1.0f);
      env_ws[tt * 1024 + c] = cur;
      cur = cur * hd;
    }
  }
}

// ---------------------------------------------------------------------------
// K3: oscillator bank. 1 WG per 256-sample chunk, 1024 channels = 1024 thr.
// In-wave reduce-scatter -> LDS partials -> plain store (no atomics).
// ---------------------------------------------------------------------------
__global__ __launch_bounds__(1024) void k3_osc(
    const double* __restrict__ r64_ws, const float* __restrict__ env_ws,
    float* __restrict__ out) {
  __shared__ float part[16][260];
  const double TWO_PI     = 6.283185307179586476925286766559;
  const double INV_TWO_PI = 0.15915494309189533576888376337251;
  int tid = threadIdx.x;
  int lane = tid & 63, w = tid >> 6;
  int c = tid;
  int k = blockIdx.x;
  int s0 = k * 256;

  double r  = r64_ws[c];
  double rr = r - rint(r * INV_TWO_PI) * TWO_PI;
  double x0 = (double)(s0 + 1) * r;
  double ph = x0 - rint(x0 * INV_TWO_PI) * TWO_PI;
  float sph, cph; __sincosf((float)ph, &sph, &cph);
  float srot, crot; __sincosf((float)rr, &srot, &crot);

  int km1 = (k > 0) ? (k - 1) : 0;
  int kp1 = (k < 127) ? (k + 1) : 127;
  float ea = env_ws[km1 * 1024 + c];
  float eb = env_ws[k   * 1024 + c];
  float ec = env_ws[kp1 * 1024 + c];

  int sb = 0;
  #pragma unroll
  for (int half = 0; half < 2; ++half) {
    float ev, slope;
    if (half == 0) { slope = (eb - ea) * (1.0f / 256.0f); ev = ea + (eb - ea) * (128.5f / 256.0f); }
    else           { slope = (ec - eb) * (1.0f / 256.0f); ev = eb + (ec - eb) * (0.5f / 256.0f); }
    for (int it = 0; it < 32; ++it) {
      float v0, v1, v2, v3, tn;
      v0 = ev * sph; tn = sph*crot + cph*srot; cph = cph*crot - sph*srot; sph = tn; ev += slope;
      v1 = ev * sph; tn = sph*crot + cph*srot; cph = cph*crot - sph*srot; sph = tn; ev += slope;
      v2 = ev * sph; tn = sph*crot + cph*srot; cph = cph*crot - sph*srot; sph = tn; ev += slope;
      v3 = ev * sph; tn = sph*crot + cph*srot; cph = cph*crot - sph*srot; sph = tn; ev += slope;
      float t0 = __shfl_xor(v0, 32);
      float t1 = __shfl_xor(v1, 32);
      float t2 = __shfl_xor(v2, 32);
      float t3 = __shfl_xor(v3, 32);
      bool b5 = (lane & 32) != 0;
      float w0 = b5 ? (v2 + t2) : (v0 + t0);
      float w1 = b5 ? (v3 + t3) : (v1 + t1);
      t0 = __shfl_xor(w0, 16);
      t1 = __shfl_xor(w1, 16);
      float xs = (lane & 16) ? (w1 + t1) : (w0 + t0);
      xs += __shfl_xor(xs, 8);
      xs += __shfl_xor(xs, 4);
      xs += __shfl_xor(xs, 2);
      xs += __shfl_xor(xs, 1);
      if ((lane & 15) == 0)
        part[w][sb + (lane >> 4)] = xs;
      sb += 4;
    }
  }
  __syncthreads();
  if (tid < 256) {
    float acc = 0.0f;
    #pragma unroll
    for (int ww = 0; ww < 16; ++ww) acc += part[ww][tid];
    out[s0 + tid] = acc * (1.0f / 1024.0f);
  }
}

// ---------------------------------------------------------------------------
// Four-step FFT, M = 16384 = 128 x 128, per batch.
// Layouts in A (ws): after kf1  A[k1*128+n2] = FFT_n1(z)[k1] * W_M^{n2 k1}
//                    after kf2  A[k1*128+k2] = Z[k1 + 128 k2]   (transposed)
//                    kfilt: in-place Hermitian-unpack * H/M * repack
//                    after ki1  A[k1*128+n2] = IFFT_k2(Z2)[n2] * W_M^{-n2 k1}
//                    ki2: column IFFT over k1 -> z2[n1*128+n2] * amp -> ws2[n]
// ---------------------------------------------------------------------------
__global__ __launch_bounds__(512) void kf1(
    const float* __restrict__ noise_u, float2* __restrict__ A) {
  __shared__ float2 zs[32 * ZROW];
  __shared__ float2 tws[64];
  int b = blockIdx.x, tile = blockIdx.y, tid = threadIdx.x;
  tw_init(tws, tid);
  const float2* nu2 = (const float2*)(noise_u + (size_t)b * NSAMP);
  for (int it = 0; it < 8; ++it) {
    int e = it * 512 + tid;
    int n1 = e >> 5, n2l = e & 31;
    float2 xv = nu2[n1 * 128 + tile * 32 + n2l];
    zs[zp(n2l, brev7(n1))] = make_float2(xv.x * 2.0f - 1.0f, xv.y * 2.0f - 1.0f);
  }
  __syncthreads();
  fft_stages<false>(zs, tws, tid);
  float2* Ab = A + (size_t)b * MFFT;
  for (int it = 0; it < 8; ++it) {
    int e = it * 512 + tid;
    int k1 = e >> 5, n2l = e & 31;
    int n2 = tile * 32 + n2l;
    float2 v = zs[zp(n2l, k1)];
    float ang = -(2.0f * (float)M_PI / 16384.0f) * (float)(k1 * n2);
    float ss, cc; __sincosf(ang, &ss, &cc);
    Ab[k1 * 128 + n2] = make_float2(cc * v.x - ss * v.y, cc * v.y + ss * v.x);
  }
}

__global__ __launch_bounds__(512) void kf2(float2* __restrict__ A) {
  __shared__ float2 zs[32 * ZROW];
  __shared__ float2 tws[64];
  int b = blockIdx.x, tile = blockIdx.y, tid = threadIdx.x;
  tw_init(tws, tid);
  float2* Ab = A + (size_t)b * MFFT + (size_t)tile * 32 * 128;
  for (int it = 0; it < 8; ++it) {
    int e = it * 512 + tid;
    int rl = e >> 7, n2 = e & 127;
    zs[zp(rl, brev7(n2))] = Ab[rl * 128 + n2];
  }
  __syncthreads();
  fft_stages<false>(zs, tws, tid);
  for (int it = 0; it < 8; ++it) {
    int e = it * 512 + tid;
    int rl = e >> 7, k2 = e & 127;
    Ab[rl * 128 + k2] = zs[zp(rl, k2)];
  }
}

__global__ __launch_bounds__(256) void kfilt(
    const float* __restrict__ packed, float2* __restrict__ A) {
  __shared__ float nf_s[64];
  int b = blockIdx.x, tid = threadIdx.x;
  const float* pk = packed + b * 480;
  if (tid < 64) nf_s[tid] = pk[416 + tid];
  __syncthreads();
  float2* Ab = A + (size_t)b * MFFT;
  const float hsc = 1.0f / (float)MFFT;
  if (blockIdx.y == 0 && tid == 0) {           // f = 0 (DC; H[M]=0 -> YM=0)
    float2 Z0 = Ab[0];
    float X0 = Z0.x + Z0.y;
    float Y0 = X0 * (h_filter(0, nf_s) * hsc);
    Ab[0] = make_float2(0.5f * Y0, 0.5f * Y0);
  }
  if (blockIdx.y == 0 && tid == 1) {           // f = M/2 -> (k1=0,k2=64)
    float Hm = h_filter(MFFT / 2, nf_s) * hsc;
    float2 Zm = Ab[64];
    Ab[64] = make_float2(Zm.x * Hm, Zm.y * Hm);
  }
  for (int it = 0; it < 16; ++it) {
    int f = 1 + tid + (blockIdx.y * 16 + it) * 256;
    if (f >= MFFT / 2) continue;
    int g = MFFT - f;
    int tf = (f & 127) * 128 + (f >> 7);
    int tg = (g & 127) * 128 + (g >> 7);
    float2 Zf = Ab[tf], Zg = Ab[tg];
    float Ax = 0.5f * (Zf.x + Zg.x), Ay = 0.5f * (Zf.y - Zg.y);
    float Bx = 0.5f * (Zf.x - Zg.x), By = 0.5f * (Zf.y + Zg.y);
    float ang = (-(float)M_PI / (float)MFFT) * (float)f;
    float ss, cc; __sincosf(ang, &ss, &cc);
    float WBx = cc * Bx - ss * By, WBy = cc * By + ss * Bx;
    float Hf = h_filter(f, nf_s) * hsc;
    float Hg = h_filter(g, nf_s) * hsc;
    float Yfx = (Ax + WBy) * Hf, Yfy = (Ay - WBx) * Hf;
    float Ygx = (Ax - WBy) * Hg, Ygy = (-Ay - WBx) * Hg;
    float A2x = 0.5f * (Yfx + Ygx), A2y = 0.5f * (Yfy - Ygy);
    float B2x = 0.5f * (Yfx - Ygx), B2y = 0.5f * (Yfy + Ygy);
    float CBx = cc * B2x + ss * B2y;
    float CBy = cc * B2y - ss * B2x;
    Ab[tf] = make_float2(A2x - CBy, A2y + CBx);
    float DBx = cc * B2x + ss * B2y;
    float DBy = ss * B2x - cc * B2y;
    Ab[tg] = make_float2(A2x - DBy, -A2y + DBx);
  }
}

__global__ __launch_bounds__(512) void ki1(float2* __restrict__ A) {
  __shared__ float2 zs[32 * ZROW];
  __shared__ float2 tws[64];
  int b = blockIdx.x, tile = blockIdx.y, tid = threadIdx.x;
  tw_init(tws, tid);
  float2* Ab = A + (size_t)b * MFFT + (size_t)tile * 32 * 128;
  for (int it = 0; it < 8; ++it) {
    int e = it * 512 + tid;
    int rl = e >> 7, k2 = e & 127;
    zs[zp(rl, brev7(k2))] = Ab[rl * 128 + k2];
  }
  __syncthreads();
  fft_stages<true>(zs, tws, tid);
  for (int it = 0; it < 8; ++it) {
    int e = it * 512 + tid;
    int rl = e >> 7, n2 = e & 127;
    int k1 = tile * 32 + rl;
    float2 v = zs[zp(rl, n2)];
    float ang = (2.0f * (float)M_PI / 16384.0f) * (float)(k1 * n2);
    float ss, cc; __sincosf(ang, &ss, &cc);
    Ab[rl * 128 + n2] = make_float2(cc * v.x - ss * v.y, cc * v.y + ss * v.x);
  }
}

__global__ __launch_bounds__(512) void ki2(
    const float* __restrict__ packed, const float2* __restrict__ A,
    float2* __restrict__ ws2) {
  __shared__ float2 zs[32 * ZROW];
  __shared__ float2 tws[64];
  __shared__ float amp_s[128];
  int b = blockIdx.x, tile = blockIdx.y, tid = threadIdx.x;
  tw_init(tws, tid);
  if (tid < 128) amp_s[tid] = packed[b * 480 + 256 + tid] * 2.0f - 1.0f;
  const float2* Ab = A + (size_t)b * MFFT;
  for (int it = 0; it < 8; ++it) {
    int e = it * 512 + tid;
    int k1 = e >> 5, n2l = e & 31;
    zs[zp(n2l, brev7(k1))] = Ab[k1 * 128 + tile * 32 + n2l];
  }
  __syncthreads();
  fft_stages<true>(zs, tws, tid);
  float2* W2 = ws2 + (size_t)b * MFFT;
  for (int it = 0; it < 8; ++it) {
    int e = it * 512 + tid;
    int n1 = e >> 5, n2l = e & 31;
    int n2 = tile * 32 + n2l;
    int n = n1 * 128 + n2;
    float2 v = zs[zp(n2l, n1)];
    v.x *= amp_lerp(2 * n,     amp_s);
    v.y *= amp_lerp(2 * n + 1, amp_s);
    W2[n] = v;
  }
}

// sum noise over batches, add to out (osc part already stored by k3)
__global__ __launch_bounds__(256) void kreduce(
    const float2* __restrict__ ws2, float* __restrict__ out) {
  int n = blockIdx.x * 256 + threadIdx.x;
  float2 acc = make_float2(0.0f, 0.0f);
  for (int b = 0; b < BATCH; ++b) {
    float2 v = ws2[(size_t)b * MFFT + n];
    acc.x += v.x; acc.y += v.y;
  }
  float2* out2 = (float2*)out;
  float2 cur = out2[n];
  out2[n] = make_float2(cur.x + acc.x * (1.0f / 64.0f),
                        cur.y + acc.y * (1.0f / 64.0f));
}

// ---------------------------------------------------------------------------
extern "C" void kernel_launch(void* const* d_in, const int* in_sizes, int n_in,
                              void* d_out, int out_size, void* d_ws, size_t ws_size,
                              hipStream_t stream) {
  const float* packed  = (const float*)d_in[0];
  const float* gumbel  = (const float*)d_in[1];
  const float* noise_u = (const float*)d_in[2];
  float* out = (float*)d_out;

  // ws layout: [r64 8KB][env 512KB][A 8MB][ws2 8MB]  (~16.5MB total)
  char* wsc = (char*)d_ws;
  double* r64_ws = (double*)wsc;
  float*  env_ws = (float*)(wsc + 8192);
  float2* A      = (float2*)(wsc + 8192 + 524288);
  float2* ws2    = (float2*)(wsc + 8192 + 524288 + (size_t)BATCH * MFFT * 8);

  k1_setup<<<BATCH, 128, 0, stream>>>(packed, gumbel, r64_ws, env_ws);
  kf1 <<<dim3(BATCH, 4), 512, 0, stream>>>(noise_u, A);
  kf2 <<<dim3(BATCH, 4), 512, 0, stream>>>(A);
  kfilt<<<dim3(BATCH, 2), 256, 0, stream>>>(packed, A);
  ki1 <<<dim3(BATCH, 4), 512, 0, stream>>>(A);
  ki2 <<<dim3(BATCH, 4), 512, 0, stream>>>(packed, A, ws2);
  k3_osc<<<128, 1024, 0, stream>>>(r64_ws, env_ws, out);   // plain stores
  kreduce<<<MFFT / 256, 256, 0, stream>>>(ws2, out);       // adds noise
}

// Round 6
// 60.406 us; speedup vs baseline: 3.5281x; 1.5797x over previous
//
#include <hip/hip_runtime.h>
#include <math.h>

#define NSAMP   32768
#define NFRAMES 128
#define NHARM   16
#define BATCH   64
#define MFFT    16384          // complex FFT size (even/odd real pack), = 128*128
#define ZROW    137            // LDS row stride (float2) for 128-entry FFT rows

static __device__ __forceinline__ float clampf(float x, float lo, float hi) {
  return fminf(fmaxf(x, lo), hi);
}
static __device__ __forceinline__ int zp(int fft, int p) {        // LDS swizzle
  return fft * ZROW + p + (p >> 4);
}
static __device__ __forceinline__ int brev7(int n) {
  return (int)(__brev((unsigned)n) >> 25);
}

// 7-stage radix-2 DIT over 32 FFTs of length 128 resident in LDS.
// Input loaded at bit-reversed positions; output natural order.
// tws[j] = (cos(-pi j/64), sin(-pi j/64)); INV conjugates the twiddle.
template <bool INV>
static __device__ __forceinline__ void fft_stages(float2* zs, const float2* tws, int tid) {
  for (int s = 0; s < 7; ++s) {
    int half = 1 << s;
    for (int j = tid; j < 2048; j += 512) {
      int fft = j >> 6, bf = j & 63;
      int kk = bf & (half - 1);
      int p0 = ((bf & ~(half - 1)) << 1) | kk;
      int p1 = p0 + half;
      float2 w = tws[kk << (6 - s)];
      float cc = w.x, ss = INV ? -w.y : w.y;
      int a0 = zp(fft, p0), a1 = zp(fft, p1);
      float2 a = zs[a0], bv = zs[a1];
      float2 t = make_float2(cc * bv.x - ss * bv.y, cc * bv.y + ss * bv.x);
      zs[a0] = make_float2(a.x + t.x, a.y + t.y);
      zs[a1] = make_float2(a.x - t.x, a.y - t.y);
    }
    __syncthreads();
  }
}

// Inverse as radix-2 DIF: natural-order input -> bit-reversed output.
// Twiddle e^{+i pi kk/half} (conj of tws entry at same index).
static __device__ __forceinline__ void fft_stages_dif_inv(float2* zs, const float2* tws, int tid) {
  for (int s = 6; s >= 0; --s) {
    int half = 1 << s;
    for (int j = tid; j < 2048; j += 512) {
      int fft = j >> 6, bf = j & 63;
      int kk = bf & (half - 1);
      int p0 = ((bf & ~(half - 1)) << 1) | kk;
      int p1 = p0 + half;
      float2 w = tws[kk << (6 - s)];
      float cc = w.x, ss = -w.y;                 // e^{+i pi kk/2^s}
      int a0 = zp(fft, p0), a1 = zp(fft, p1);
      float2 u = zs[a0], v = zs[a1];
      zs[a0] = make_float2(u.x + v.x, u.y + v.y);
      float dx = u.x - v.x, dy = u.y - v.y;
      zs[a1] = make_float2(cc * dx - ss * dy, cc * dy + ss * dx);
    }
    __syncthreads();
  }
}

static __device__ __forceinline__ void tw_init(float2* tws, int tid) {
  if (tid < 64) {
    float s, c;
    __sincosf(-(float)M_PI * (float)tid * (1.0f / 64.0f), &s, &c);
    tws[tid] = make_float2(c, s);
  }
}

static __device__ __forceinline__ float h_filter(int f, const float* nf_s) {
  float coords = ((float)f + 0.5f) * (1.0f / 256.0f) - 0.5f;
  coords = clampf(coords, 0.0f, 63.0f);
  int i0 = (int)coords;
  int i1 = (i0 < 63) ? (i0 + 1) : 63;
  float w = coords - (float)i0;
  return nf_s[i0] * (1.0f - w) + nf_s[i1] * w;
}

static __device__ __forceinline__ float amp_lerp(int s, const float* amp_s) {
  float coords = ((float)s + 0.5f) * (1.0f / 256.0f) - 0.5f;
  coords = clampf(coords, 0.0f, 127.0f);
  int i0 = (int)coords;
  int i1 = (i0 < 127) ? (i0 + 1) : 127;
  float w = coords - (float)i0;
  float v = amp_s[i0] * (1.0f - w) + amp_s[i1] * w;
  return clampf(v, 0.0f, 1.0f);
}

// ---------------------------------------------------------------------------
// K1: gumbel argmax -> f0 -> per-harmonic radians (f64); 128-frame env scan.
// env layout: env_ws[frame*1024 + channel]
// ---------------------------------------------------------------------------
__global__ __launch_bounds__(128) void k1_setup(
    const float* __restrict__ packed, const float* __restrict__ gumbel,
    double* __restrict__ r64_ws, float* __restrict__ env_ws) {
  __shared__ double zv[128];
  __shared__ int    zi[128];
  __shared__ double f0_sh;
  int b = blockIdx.x, tid = threadIdx.x;
  const float* pk = packed + b * 480;

  double u = (double)gumbel[b * 128 + tid];
  double t = -log(u + 1e-10);
  double g = -log(t + 1e-10);
  zv[tid] = (double)pk[tid] + g;
  zi[tid] = tid;
  __syncthreads();
  for (int s = 64; s > 0; s >>= 1) {
    if (tid < s) {
      double a = zv[tid], c = zv[tid + s];
      int ia = zi[tid], ic = zi[tid + s];
      if (c > a || (c == a && ic < ia)) { zv[tid] = c; zi[tid] = ic; }
    }
    __syncthreads();
  }
  if (tid == 0) {
    int note = zi[0];
    double Fd  = 440.0 * exp2(((double)(note - 69)) / 12.0) / 11025.0;
    float  F32 = (float)Fd;                     // FREQS is f32 in the reference
    double f0  = (double)F32 * 11025.0;
    f0 = (40.0 / 11025.0) + f0 * (3000.0 / 11025.0 - 40.0 / 11025.0);
    f0_sh = f0;
  }
  __syncthreads();
  if (tid < NHARM) {
    int h = tid;
    int c = b * NHARM + h;
    const float PIF = 3.14159265358979323846f;  // float32(np.pi)
    double osc = f0_sh * (double)(h + 1);
    r64_ws[c] = (osc / 11025.0) * (double)PIF;
    float ha = pk[384 + h];
    float hd = 0.1f + pk[400 + h] * 0.9f;
    float cur = 0.0f;
    for (int tt = 0; tt < NFRAMES; ++tt) {
      float a = pk[256 + tt] * 2.0f - 1.0f;
      cur = clampf(cur + a * ha, 0.0f, 1.0f);
      env_ws[tt * 1024 + c] = cur;
      cur = cur * hd;
    }
  }
}

// ---------------------------------------------------------------------------
// kf1: column FFTs (length 128 over n1) + W_M^{n2 k1} twiddle.
// A[k1*128 + n2] output.  grid (BATCH, 4) x 512
// ---------------------------------------------------------------------------
__global__ __launch_bounds__(512) void kf1(
    const float* __restrict__ noise_u, float2* __restrict__ A) {
  __shared__ float2 zs[32 * ZROW];
  __shared__ float2 tws[64];
  int b = blockIdx.x, tile = blockIdx.y, tid = threadIdx.x;
  tw_init(tws, tid);
  const float2* nu2 = (const float2*)(noise_u + (size_t)b * NSAMP);
  for (int it = 0; it < 8; ++it) {
    int e = it * 512 + tid;
    int n1 = e >> 5, n2l = e & 31;
    float2 xv = nu2[n1 * 128 + tile * 32 + n2l];
    zs[zp(n2l, brev7(n1))] = make_float2(xv.x * 2.0f - 1.0f, xv.y * 2.0f - 1.0f);
  }
  __syncthreads();
  fft_stages<false>(zs, tws, tid);
  float2* Ab = A + (size_t)b * MFFT;
  for (int it = 0; it < 8; ++it) {
    int e = it * 512 + tid;
    int k1 = e >> 5, n2l = e & 31;
    int n2 = tile * 32 + n2l;
    float2 v = zs[zp(n2l, k1)];
    float ang = -(2.0f * (float)M_PI / 16384.0f) * (float)(k1 * n2);
    float ss, cc; __sincosf(ang, &ss, &cc);
    Ab[k1 * 128 + n2] = make_float2(cc * v.x - ss * v.y, cc * v.y + ss * v.x);
  }
}

// ---------------------------------------------------------------------------
// kmid: fused row-FFT (fwd) -> Hermitian filter (in LDS) -> row-IFFT (DIF)
//       -> conj twiddle W_M^{+k1 n2}.  Each WG holds 16 row-pair groups:
//       group m = {k1=m, k1=128-m}; group 0 = {0, 64} (self-paired rows).
// grid (BATCH, 4) x 512
// ---------------------------------------------------------------------------
__global__ __launch_bounds__(512) void kmid(
    const float* __restrict__ packed, float2* __restrict__ A) {
  __shared__ float2 zs[32 * ZROW];
  __shared__ float2 tws[64];
  __shared__ float  nf_s[64];
  __shared__ int    rowk1[32];
  int b = blockIdx.x, t = blockIdx.y, tid = threadIdx.x;
  tw_init(tws, tid);
  if (tid >= 64 && tid < 128) nf_s[tid - 64] = packed[b * 480 + 416 + (tid - 64)];
  if (tid < 32) {
    int s = tid & 15;
    int m = t * 16 + s;
    rowk1[tid] = (tid < 16) ? m : ((m == 0) ? 64 : 128 - m);
  }
  __syncthreads();
  float2* Ab = A + (size_t)b * MFFT;

  // load 32 rows, bitrev over the row coordinate (k2 direction)
  for (int it = 0; it < 8; ++it) {
    int e = it * 512 + tid;
    int r = e >> 7, n2 = e & 127;
    zs[zp(r, brev7(n2))] = Ab[rowk1[r] * 128 + n2];
  }
  __syncthreads();
  fft_stages<false>(zs, tws, tid);   // zs[zp(r,k2)] = Z[rowk1[r] + 128*k2]

  // Hermitian unpack * H/M * repack, all pairs LDS-resident.
  const float hsc = 1.0f / 16384.0f;
  for (int it = 0; it < 4; ++it) {
    int task = it * 512 + tid;      // 2048 tasks: (local row r, k2 in 0..63)
    int r  = task >> 6;
    int k2 = task & 63;
    int k1 = rowk1[r];
    int f = k1 + (k2 << 7);         // f in [0, 8191]
    if (f == 0) {                   // DC (and M/2 bin at row 0, k2=64)
      float2 Z0 = zs[zp(0, 0)];
      float X0 = Z0.x + Z0.y;
      float Y0 = X0 * (h_filter(0, nf_s) * hsc);
      zs[zp(0, 0)] = make_float2(0.5f * Y0, 0.5f * Y0);   // H[M]=0 -> YM=0
      float Hm = h_filter(8192, nf_s) * hsc;
      float2 Zm = zs[zp(0, 64)];
      zs[zp(0, 64)] = make_float2(Zm.x * Hm, Zm.y * Hm);
    } else {
      int g = 16384 - f;
      int k1g = g & 127;
      int pr = (k1g == k1) ? r : ((r < 16) ? r + 16 : r - 16);
      int k2p = g >> 7;
      float2 Zf = zs[zp(r, k2)], Zg = zs[zp(pr, k2p)];
      float Ax = 0.5f * (Zf.x + Zg.x), Ay = 0.5f * (Zf.y - Zg.y);
      float Bx = 0.5f * (Zf.x - Zg.x), By = 0.5f * (Zf.y + Zg.y);
      float ang = (-(float)M_PI / (float)MFFT) * (float)f;
      float ss, cc; __sincosf(ang, &ss, &cc);
      float WBx = cc * Bx - ss * By, WBy = cc * By + ss * Bx;
      float Hf = h_filter(f, nf_s) * hsc;
      float Hg = h_filter(g, nf_s) * hsc;
      float Yfx = (Ax + WBy) * Hf, Yfy = (Ay - WBx) * Hf;
      float Ygx = (Ax - WBy) * Hg, Ygy = (-Ay - WBx) * Hg;
      float A2x = 0.5f * (Yfx + Ygx), A2y = 0.5f * (Yfy - Ygy);
      float B2x = 0.5f * (Yfx - Ygx), B2y = 0.5f * (Yfy + Ygy);
      float CBx = cc * B2x + ss * B2y;
      float CBy = cc * B2y - ss * B2x;
      zs[zp(r, k2)]    = make_float2(A2x - CBy, A2y + CBx);
      float DBx = cc * B2x + ss * B2y;
      float DBy = ss * B2x - cc * B2y;
      zs[zp(pr, k2p)]  = make_float2(A2x - DBy, -A2y + DBx);
    }
  }
  __syncthreads();

  fft_stages_dif_inv(zs, tws, tid);  // natural -> bitrev

  // store, un-bitrev + conj twiddle
  for (int it = 0; it < 8; ++it) {
    int e = it * 512 + tid;
    int r = e >> 7, n2 = e & 127;
    int k1 = rowk1[r];
    float2 v = zs[zp(r, brev7(n2))];
    float ang = (2.0f * (float)M_PI / 16384.0f) * (float)(k1 * n2);
    float ss, cc; __sincosf(ang, &ss, &cc);
    Ab[k1 * 128 + n2] = make_float2(cc * v.x - ss * v.y, cc * v.y + ss * v.x);
  }
}

// ---------------------------------------------------------------------------
// ki2: column inverse FFTs (over k1) + amp*clip -> ws2 (per-batch samples).
// grid (BATCH, 4) x 512
// ---------------------------------------------------------------------------
__global__ __launch_bounds__(512) void ki2(
    const float* __restrict__ packed, const float2* __restrict__ A,
    float2* __restrict__ ws2) {
  __shared__ float2 zs[32 * ZROW];
  __shared__ float2 tws[64];
  __shared__ float amp_s[128];
  int b = blockIdx.x, tile = blockIdx.y, tid = threadIdx.x;
  tw_init(tws, tid);
  if (tid < 128) amp_s[tid] = packed[b * 480 + 256 + tid] * 2.0f - 1.0f;
  const float2* Ab = A + (size_t)b * MFFT;
  for (int it = 0; it < 8; ++it) {
    int e = it * 512 + tid;
    int k1 = e >> 5, n2l = e & 31;
    zs[zp(n2l, brev7(k1))] = Ab[k1 * 128 + tile * 32 + n2l];
  }
  __syncthreads();
  fft_stages<true>(zs, tws, tid);
  float2* W2 = ws2 + (size_t)b * MFFT;
  for (int it = 0; it < 8; ++it) {
    int e = it * 512 + tid;
    int n1 = e >> 5, n2l = e & 31;
    int n2 = tile * 32 + n2l;
    int n = n1 * 128 + n2;
    float2 v = zs[zp(n2l, n1)];
    v.x *= amp_lerp(2 * n,     amp_s);
    v.y *= amp_lerp(2 * n + 1, amp_s);
    W2[n] = v;
  }
}

// ---------------------------------------------------------------------------
// k3r: oscillator bank + batch-mean of noise, fused.  256 WGs x 1024 thr;
// WG k handles 128 samples (one linear env segment). ws2 viewed as flat
// floats is noise[b][s].
// ---------------------------------------------------------------------------
__global__ __launch_bounds__(1024) void k3r(
    const double* __restrict__ r64_ws, const float* __restrict__ env_ws,
    const float* __restrict__ ws2f, float* __restrict__ out) {
  __shared__ float part[16][132];
  __shared__ float nse[8][128];
  const double TWO_PI     = 6.283185307179586476925286766559;
  const double INV_TWO_PI = 0.15915494309189533576888376337251;
  int tid = threadIdx.x;
  int lane = tid & 63, w = tid >> 6;
  int c = tid;                       // channel = b*16 + h
  int k = blockIdx.x;                // 128-sample chunk
  int s0 = k * 128;
  int K = k >> 1;                    // 256-sample frame-chunk index

  double r  = r64_ws[c];
  double rr = r - rint(r * INV_TWO_PI) * TWO_PI;
  double x0 = (double)(s0 + 1) * r;
  double ph = x0 - rint(x0 * INV_TWO_PI) * TWO_PI;
  float sph, cph; __sincosf((float)ph, &sph, &cph);
  float srot, crot; __sincosf((float)rr, &srot, &crot);

  int km1 = (K > 0) ? (K - 1) : 0;
  int kp1 = (K < 127) ? (K + 1) : 127;
  float ea = env_ws[km1 * 1024 + c];
  float eb = env_ws[K   * 1024 + c];
  float ec = env_ws[kp1 * 1024 + c];
  float ev, slope;
  if ((k & 1) == 0) { slope = (eb - ea) * (1.0f / 256.0f); ev = ea + (eb - ea) * (128.5f / 256.0f); }
  else              { slope = (ec - eb) * (1.0f / 256.0f); ev = eb + (ec - eb) * (0.5f / 256.0f); }

  int sb = 0;
  for (int it = 0; it < 32; ++it) {
    float v0, v1, v2, v3, tn;
    v0 = ev * sph; tn = sph*crot + cph*srot; cph = cph*crot - sph*srot; sph = tn; ev += slope;
    v1 = ev * sph; tn = sph*crot + cph*srot; cph = cph*crot - sph*srot; sph = tn; ev += slope;
    v2 = ev * sph; tn = sph*crot + cph*srot; cph = cph*crot - sph*srot; sph = tn; ev += slope;
    v3 = ev * sph; tn = sph*crot + cph*srot; cph = cph*crot - sph*srot; sph = tn; ev += slope;
    float t0 = __shfl_xor(v0, 32);
    float t1 = __shfl_xor(v1, 32);
    float t2 = __shfl_xor(v2, 32);
    float t3 = __shfl_xor(v3, 32);
    bool b5 = (lane & 32) != 0;
    float w0 = b5 ? (v2 + t2) : (v0 + t0);
    float w1 = b5 ? (v3 + t3) : (v1 + t1);
    t0 = __shfl_xor(w0, 16);
    t1 = __shfl_xor(w1, 16);
    float xs = (lane & 16) ? (w1 + t1) : (w0 + t0);
    xs += __shfl_xor(xs, 8);
    xs += __shfl_xor(xs, 4);
    xs += __shfl_xor(xs, 2);
    xs += __shfl_xor(xs, 1);
    if ((lane & 15) == 0)
      part[w][sb + (lane >> 4)] = xs;
    sb += 4;
  }
  __syncthreads();

  // batch-mean of noise: 8 groups x 8 batches each
  {
    int j = tid & 127, grp = tid >> 7;
    const float* src = ws2f + (size_t)(grp * 8) * NSAMP + s0 + j;
    float acc = 0.0f;
    #pragma unroll
    for (int bb = 0; bb < 8; ++bb) acc += src[(size_t)bb * NSAMP];
    nse[grp][j] = acc;
  }
  __syncthreads();

  if (tid < 128) {
    float osc = 0.0f;
    #pragma unroll
    for (int ww = 0; ww < 16; ++ww) osc += part[ww][tid];
    float nz = 0.0f;
    #pragma unroll
    for (int g = 0; g < 8; ++g) nz += nse[g][tid];
    out[s0 + tid] = osc * (1.0f / 1024.0f) + nz * (1.0f / 64.0f);
  }
}

// ---------------------------------------------------------------------------
extern "C" void kernel_launch(void* const* d_in, const int* in_sizes, int n_in,
                              void* d_out, int out_size, void* d_ws, size_t ws_size,
                              hipStream_t stream) {
  const float* packed  = (const float*)d_in[0];
  const float* gumbel  = (const float*)d_in[1];
  const float* noise_u = (const float*)d_in[2];
  float* out = (float*)d_out;

  // ws layout: [r64 8KB][env 512KB][A 8MB][ws2 8MB]
  char* wsc = (char*)d_ws;
  double* r64_ws = (double*)wsc;
  float*  env_ws = (float*)(wsc + 8192);
  float2* A      = (float2*)(wsc + 8192 + 524288);
  float2* ws2    = (float2*)(wsc + 8192 + 524288 + (size_t)BATCH * MFFT * 8);

  k1_setup<<<BATCH, 128, 0, stream>>>(packed, gumbel, r64_ws, env_ws);
  kf1 <<<dim3(BATCH, 4), 512, 0, stream>>>(noise_u, A);
  kmid<<<dim3(BATCH, 4), 512, 0, stream>>>(packed, A);
  ki2 <<<dim3(BATCH, 4), 512, 0, stream>>>(packed, A, ws2);
  k3r <<<256, 1024, 0, stream>>>(r64_ws, env_ws, (const float*)ws2, out);
}

// Round 7
// 53.813 us; speedup vs baseline: 3.9604x; 1.1225x over previous
//
#include <hip/hip_runtime.h>
#include <math.h>

#define NSAMP   32768
#define NFRAMES 128
#define NHARM   16
#define BATCH   64
#define MFFT    16384          // complex FFT size (even/odd real pack), = 128*128
#define ZROW    137            // LDS row stride (float2) per 128-entry FFT row

static __device__ __forceinline__ float clampf(float x, float lo, float hi) {
  return fminf(fmaxf(x, lo), hi);
}
static __device__ __forceinline__ int zp(int fft, int p) {        // LDS swizzle
  return fft * ZROW + p + (p >> 4);
}
static __device__ __forceinline__ int brev7(int n) {
  return (int)(__brev((unsigned)n) >> 25);
}
static __device__ __forceinline__ float2 cmulf(float c, float s, float2 v) {
  return make_float2(c * v.x - s * v.y, c * v.y + s * v.x);
}
static __device__ __forceinline__ float2 f2add(float2 a, float2 b) {
  return make_float2(a.x + b.x, a.y + b.y);
}
static __device__ __forceinline__ float2 f2sub(float2 a, float2 b) {
  return make_float2(a.x - b.x, a.y - b.y);
}

static __device__ __forceinline__ void tw_init(float2* tws, int tid) {
  if (tid < 64) {
    float s, c;
    __sincosf(-(float)M_PI * (float)tid * (1.0f / 64.0f), &s, &c);
    tws[tid] = make_float2(c, s);
  }
}

// ---------------------------------------------------------------------------
// 8 FFTs of length 128 in LDS, 256 threads, one radix-4 quad per thread per
// pass (3 radix-4 passes + 1 radix-2). DIT: bit-reversed input -> natural
// output. Op-for-op identical to the radix-2 chain, fused in registers.
// tws[j] = e^{-i pi j/64}; INV conjugates. Second butterfly of each fused
// pair uses w2b = (fwd) -i*w2a / (inv) +i*w2a  [table[j+32] identity].
// ---------------------------------------------------------------------------
template <bool INV>
static __device__ __forceinline__ void fft128_r4(float2* zs, const float2* tws, int tid) {
  int fft = tid >> 5, i = tid & 31;
  #pragma unroll
  for (int s = 0; s < 6; s += 2) {
    int half = 1 << s;
    int kk1 = i & (half - 1);
    int base = ((i & ~(half - 1)) << 2) | kk1;
    int p0 = zp(fft, base),            p1 = zp(fft, base + half);
    int p2 = zp(fft, base + 2 * half), p3 = zp(fft, base + 3 * half);
    float2 q0 = zs[p0], q1 = zs[p1], q2 = zs[p2], q3 = zs[p3];
    float2 t1 = tws[kk1 << (6 - s)], t2 = tws[kk1 << (5 - s)];
    float c1 = t1.x, s1 = INV ? -t1.y : t1.y;
    float c2 = t2.x, s2 = INV ? -t2.y : t2.y;
    float c2b = INV ? -s2 : s2, s2b = INV ? c2 : -c2;
    float2 t;
    t = cmulf(c1, s1, q1);   float2 A0 = f2add(q0, t), A1 = f2sub(q0, t);
    t = cmulf(c1, s1, q3);   float2 A2 = f2add(q2, t), A3 = f2sub(q2, t);
    t = cmulf(c2, s2, A2);   zs[p0] = f2add(A0, t); zs[p2] = f2sub(A0, t);
    t = cmulf(c2b, s2b, A3); zs[p1] = f2add(A1, t); zs[p3] = f2sub(A1, t);
    __syncthreads();
  }
  #pragma unroll
  for (int j = tid; j < 512; j += 256) {        // stage 6, radix-2
    int f = j >> 6, kk = j & 63;
    float2 w = tws[kk];
    float cc = w.x, ss = INV ? -w.y : w.y;
    int a0 = zp(f, kk), a1 = zp(f, kk + 64);
    float2 a = zs[a0], bv = zs[a1];
    float2 t = cmulf(cc, ss, bv);
    zs[a0] = f2add(a, t); zs[a1] = f2sub(a, t);
  }
  __syncthreads();
}

// Inverse as DIF: natural input -> bit-reversed output. Stage 6 first, then
// fused stage-pairs (5,4),(3,2),(1,0). Twiddles conjugated; w2b = +i*w2a.
static __device__ __forceinline__ void fft128_r4_dif_inv(float2* zs, const float2* tws, int tid) {
  #pragma unroll
  for (int j = tid; j < 512; j += 256) {        // stage 6, radix-2 DIF
    int f = j >> 6, kk = j & 63;
    float2 w = tws[kk];
    float cc = w.x, ss = -w.y;
    int a0 = zp(f, kk), a1 = zp(f, kk + 64);
    float2 u = zs[a0], v = zs[a1];
    zs[a0] = f2add(u, v);
    zs[a1] = cmulf(cc, ss, f2sub(u, v));
  }
  __syncthreads();
  int fft = tid >> 5, i = tid & 31;
  #pragma unroll
  for (int s = 4; s >= 0; s -= 2) {
    int half = 1 << s;
    int kk1 = i & (half - 1);
    int base = ((i & ~(half - 1)) << 2) | kk1;
    int p0 = zp(fft, base),            p1 = zp(fft, base + half);
    int p2 = zp(fft, base + 2 * half), p3 = zp(fft, base + 3 * half);
    float2 q0 = zs[p0], q1 = zs[p1], q2 = zs[p2], q3 = zs[p3];
    float2 t1 = tws[kk1 << (6 - s)], t2 = tws[kk1 << (5 - s)];
    float c1 = t1.x, s1 = -t1.y;
    float c2 = t2.x, s2 = -t2.y;
    float c2b = -s2, s2b = c2;                  // +i * (c2, s2)
    float2 B0 = f2add(q0, q2);
    float2 B2 = cmulf(c2, s2, f2sub(q0, q2));
    float2 B1 = f2add(q1, q3);
    float2 B3 = cmulf(c2b, s2b, f2sub(q1, q3));
    zs[p0] = f2add(B0, B1);
    zs[p1] = cmulf(c1, s1, f2sub(B0, B1));
    zs[p2] = f2add(B2, B3);
    zs[p3] = cmulf(c1, s1, f2sub(B2, B3));
    __syncthreads();
  }
}

static __device__ __forceinline__ float h_filter(int f, const float* nf_s) {
  float coords = ((float)f + 0.5f) * (1.0f / 256.0f) - 0.5f;
  coords = clampf(coords, 0.0f, 63.0f);
  int i0 = (int)coords;
  int i1 = (i0 < 63) ? (i0 + 1) : 63;
  float w = coords - (float)i0;
  return nf_s[i0] * (1.0f - w) + nf_s[i1] * w;
}

static __device__ __forceinline__ float amp_lerp(int s, const float* amp_s) {
  float coords = ((float)s + 0.5f) * (1.0f / 256.0f) - 0.5f;
  coords = clampf(coords, 0.0f, 127.0f);
  int i0 = (int)coords;
  int i1 = (i0 < 127) ? (i0 + 1) : 127;
  float w = coords - (float)i0;
  float v = amp_s[i0] * (1.0f - w) + amp_s[i1] * w;
  return clampf(v, 0.0f, 1.0f);
}

// ---------------------------------------------------------------------------
// K1: gumbel argmax -> f0 -> per-harmonic radians (f64); 128-frame env scan.
// env layout: env_ws[frame*1024 + channel]
// ---------------------------------------------------------------------------
__global__ __launch_bounds__(128) void k1_setup(
    const float* __restrict__ packed, const float* __restrict__ gumbel,
    double* __restrict__ r64_ws, float* __restrict__ env_ws) {
  __shared__ double zv[128];
  __shared__ int    zi[128];
  __shared__ double f0_sh;
  int b = blockIdx.x, tid = threadIdx.x;
  const float* pk = packed + b * 480;

  double u = (double)gumbel[b * 128 + tid];
  double t = -log(u + 1e-10);
  double g = -log(t + 1e-10);
  zv[tid] = (double)pk[tid] + g;
  zi[tid] = tid;
  __syncthreads();
  for (int s = 64; s > 0; s >>= 1) {
    if (tid < s) {
      double a = zv[tid], c = zv[tid + s];
      int ia = zi[tid], ic = zi[tid + s];
      if (c > a || (c == a && ic < ia)) { zv[tid] = c; zi[tid] = ic; }
    }
    __syncthreads();
  }
  if (tid == 0) {
    int note = zi[0];
    double Fd  = 440.0 * exp2(((double)(note - 69)) / 12.0) / 11025.0;
    float  F32 = (float)Fd;                     // FREQS is f32 in the reference
    double f0  = (double)F32 * 11025.0;
    f0 = (40.0 / 11025.0) + f0 * (3000.0 / 11025.0 - 40.0 / 11025.0);
    f0_sh = f0;
  }
  __syncthreads();
  if (tid < NHARM) {
    int h = tid;
    int c = b * NHARM + h;
    const float PIF = 3.14159265358979323846f;  // float32(np.pi)
    double osc = f0_sh * (double)(h + 1);
    r64_ws[c] = (osc / 11025.0) * (double)PIF;
    float ha = pk[384 + h];
    float hd = 0.1f + pk[400 + h] * 0.9f;
    float cur = 0.0f;
    for (int tt = 0; tt < NFRAMES; ++tt) {
      float a = pk[256 + tt] * 2.0f - 1.0f;
      cur = clampf(cur + a * ha, 0.0f, 1.0f);
      env_ws[tt * 1024 + c] = cur;
      cur = cur * hd;
    }
  }
}

// ---------------------------------------------------------------------------
// kf1: column FFTs (length 128 over n1) + W_M^{n2 k1} twiddle.
// grid (BATCH, 16) x 256; 8 columns per WG.
// ---------------------------------------------------------------------------
__global__ __launch_bounds__(256, 4) void kf1(
    const float* __restrict__ noise_u, float2* __restrict__ A) {
  __shared__ float2 zs[8 * ZROW];
  __shared__ float2 tws[64];
  int b = blockIdx.x, tile = blockIdx.y, tid = threadIdx.x;
  tw_init(tws, tid);
  const float2* nu2 = (const float2*)(noise_u + (size_t)b * NSAMP);
  #pragma unroll
  for (int it = 0; it < 4; ++it) {
    int e = it * 256 + tid;
    int n1 = e >> 3, n2l = e & 7;
    float2 xv = nu2[n1 * 128 + tile * 8 + n2l];
    zs[zp(n2l, brev7(n1))] = make_float2(xv.x * 2.0f - 1.0f, xv.y * 2.0f - 1.0f);
  }
  __syncthreads();
  fft128_r4<false>(zs, tws, tid);
  float2* Ab = A + (size_t)b * MFFT;
  #pragma unroll
  for (int it = 0; it < 4; ++it) {
    int e = it * 256 + tid;
    int k1 = e >> 3, n2l = e & 7;
    int n2 = tile * 8 + n2l;
    float2 v = zs[zp(n2l, k1)];
    float ang = -(2.0f * (float)M_PI / 16384.0f) * (float)(k1 * n2);
    float ss, cc; __sincosf(ang, &ss, &cc);
    Ab[k1 * 128 + n2] = make_float2(cc * v.x - ss * v.y, cc * v.y + ss * v.x);
  }
}

// ---------------------------------------------------------------------------
// kmid: fused row-FFT (fwd) -> Hermitian filter (in LDS) -> row-IFFT (DIF)
//       -> conj twiddle W_M^{+k1 n2}.  8 rows = 4 pair-groups per WG:
//       rows {t*4+j} paired with {128-(t*4+j)} (m=0 pairs with row 64).
// grid (BATCH, 16) x 256
// ---------------------------------------------------------------------------
__global__ __launch_bounds__(256, 4) void kmid(
    const float* __restrict__ packed, float2* __restrict__ A) {
  __shared__ float2 zs[8 * ZROW];
  __shared__ float2 tws[64];
  __shared__ float  nf_s[64];
  __shared__ int    rowk1[8];
  int b = blockIdx.x, t = blockIdx.y, tid = threadIdx.x;
  tw_init(tws, tid);
  if (tid >= 64 && tid < 128) nf_s[tid - 64] = packed[b * 480 + 416 + (tid - 64)];
  if (tid < 8) {
    int s = tid & 3;
    int m = t * 4 + s;
    rowk1[tid] = (tid < 4) ? m : ((m == 0) ? 64 : 128 - m);
  }
  __syncthreads();
  float2* Ab = A + (size_t)b * MFFT;

  // load 8 rows, bitrev over k2
  #pragma unroll
  for (int it = 0; it < 4; ++it) {
    int e = it * 256 + tid;
    int r = e >> 7, n2 = e & 127;
    zs[zp(r, brev7(n2))] = Ab[rowk1[r] * 128 + n2];
  }
  __syncthreads();
  fft128_r4<false>(zs, tws, tid);   // zs[zp(r,k2)] = Z[rowk1[r] + 128*k2]

  // Hermitian unpack * H/M * repack; pair (k1,k2) <-> (128-k1, 127-k2),
  // row-0/row-64 pairs internal. Each unordered pair owned by ONE task.
  const float hsc = 1.0f / 16384.0f;
  #pragma unroll
  for (int it = 0; it < 2; ++it) {
    int task = it * 256 + tid;      // 512 tasks: (local row r, k2 in 0..63)
    int r  = task >> 6;
    int k2 = task & 63;
    int k1 = rowk1[r];
    int f = k1 + (k2 << 7);
    if (f == 0) {                   // DC and f=8192 specials
      float2 Z0 = zs[zp(0, 0)];
      float X0 = Z0.x + Z0.y;
      float Y0 = X0 * (h_filter(0, nf_s) * hsc);
      zs[zp(0, 0)] = make_float2(0.5f * Y0, 0.5f * Y0);   // H[M]=0 -> YM=0
      float Hm = h_filter(8192, nf_s) * hsc;
      float2 Zm = zs[zp(0, 64)];
      zs[zp(0, 64)] = make_float2(Zm.x * Hm, Zm.y * Hm);
    } else {
      int g = 16384 - f;
      int k1g = g & 127;
      int pr = (k1g == k1) ? r : ((r < 4) ? r + 4 : r - 4);
      int k2p = g >> 7;
      float2 Zf = zs[zp(r, k2)], Zg = zs[zp(pr, k2p)];
      float Ax = 0.5f * (Zf.x + Zg.x), Ay = 0.5f * (Zf.y - Zg.y);
      float Bx = 0.5f * (Zf.x - Zg.x), By = 0.5f * (Zf.y + Zg.y);
      float ang = (-(float)M_PI / (float)MFFT) * (float)f;
      float ss, cc; __sincosf(ang, &ss, &cc);
      float WBx = cc * Bx - ss * By, WBy = cc * By + ss * Bx;
      float Hf = h_filter(f, nf_s) * hsc;
      float Hg = h_filter(g, nf_s) * hsc;
      float Yfx = (Ax + WBy) * Hf, Yfy = (Ay - WBx) * Hf;
      float Ygx = (Ax - WBy) * Hg, Ygy = (-Ay - WBx) * Hg;
      float A2x = 0.5f * (Yfx + Ygx), A2y = 0.5f * (Yfy - Ygy);
      float B2x = 0.5f * (Yfx - Ygx), B2y = 0.5f * (Yfy + Ygy);
      float CBx = cc * B2x + ss * B2y;
      float CBy = cc * B2y - ss * B2x;
      zs[zp(r, k2)]   = make_float2(A2x - CBy, A2y + CBx);
      float DBx = cc * B2x + ss * B2y;
      float DBy = ss * B2x - cc * B2y;
      zs[zp(pr, k2p)] = make_float2(A2x - DBy, -A2y + DBx);
    }
  }
  __syncthreads();

  fft128_r4_dif_inv(zs, tws, tid);  // natural -> bitrev

  // store, un-bitrev + conj twiddle
  #pragma unroll
  for (int it = 0; it < 4; ++it) {
    int e = it * 256 + tid;
    int r = e >> 7, n2 = e & 127;
    int k1 = rowk1[r];
    float2 v = zs[zp(r, brev7(n2))];
    float ang = (2.0f * (float)M_PI / 16384.0f) * (float)(k1 * n2);
    float ss, cc; __sincosf(ang, &ss, &cc);
    Ab[k1 * 128 + n2] = make_float2(cc * v.x - ss * v.y, cc * v.y + ss * v.x);
  }
}

// ---------------------------------------------------------------------------
// ki2: column inverse FFTs (over k1) + amp*clip -> ws2 (per-batch samples).
// grid (BATCH, 16) x 256; 8 columns per WG.
// ---------------------------------------------------------------------------
__global__ __launch_bounds__(256, 4) void ki2(
    const float* __restrict__ packed, const float2* __restrict__ A,
    float2* __restrict__ ws2) {
  __shared__ float2 zs[8 * ZROW];
  __shared__ float2 tws[64];
  __shared__ float amp_s[128];
  int b = blockIdx.x, tile = blockIdx.y, tid = threadIdx.x;
  tw_init(tws, tid);
  if (tid >= 128 && tid < 256) amp_s[tid - 128] = packed[b * 480 + 256 + (tid - 128)] * 2.0f - 1.0f;
  const float2* Ab = A + (size_t)b * MFFT;
  #pragma unroll
  for (int it = 0; it < 4; ++it) {
    int e = it * 256 + tid;
    int k1 = e >> 3, n2l = e & 7;
    zs[zp(n2l, brev7(k1))] = Ab[k1 * 128 + tile * 8 + n2l];
  }
  __syncthreads();
  fft128_r4<true>(zs, tws, tid);
  float2* W2 = ws2 + (size_t)b * MFFT;
  #pragma unroll
  for (int it = 0; it < 4; ++it) {
    int e = it * 256 + tid;
    int n1 = e >> 3, n2l = e & 7;
    int n2 = tile * 8 + n2l;
    int n = n1 * 128 + n2;
    float2 v = zs[zp(n2l, n1)];
    v.x *= amp_lerp(2 * n,     amp_s);
    v.y *= amp_lerp(2 * n + 1, amp_s);
    W2[n] = v;
  }
}

// ---------------------------------------------------------------------------
// k3r: oscillator bank + batch-mean of noise, fused.  256 WGs x 1024 thr;
// WG k handles 128 samples. ws2 viewed as flat floats is noise[b][s].
// ---------------------------------------------------------------------------
__global__ __launch_bounds__(1024) void k3r(
    const double* __restrict__ r64_ws, const float* __restrict__ env_ws,
    const float* __restrict__ ws2f, float* __restrict__ out) {
  __shared__ float part[16][132];
  __shared__ float nse[8][128];
  const double TWO_PI     = 6.283185307179586476925286766559;
  const double INV_TWO_PI = 0.15915494309189533576888376337251;
  int tid = threadIdx.x;
  int lane = tid & 63, w = tid >> 6;
  int c = tid;                       // channel = b*16 + h
  int k = blockIdx.x;                // 128-sample chunk
  int s0 = k * 128;
  int K = k >> 1;                    // 256-sample frame-chunk index

  double r  = r64_ws[c];
  double rr = r - rint(r * INV_TWO_PI) * TWO_PI;
  double x0 = (double)(s0 + 1) * r;
  double ph = x0 - rint(x0 * INV_TWO_PI) * TWO_PI;
  float sph, cph; __sincosf((float)ph, &sph, &cph);
  float srot, crot; __sincosf((float)rr, &srot, &crot);

  int km1 = (K > 0) ? (K - 1) : 0;
  int kp1 = (K < 127) ? (K + 1) : 127;
  float ea = env_ws[km1 * 1024 + c];
  float eb = env_ws[K   * 1024 + c];
  float ec = env_ws[kp1 * 1024 + c];
  float ev, slope;
  if ((k & 1) == 0) { slope = (eb - ea) * (1.0f / 256.0f); ev = ea + (eb - ea) * (128.5f / 256.0f); }
  else              { slope = (ec - eb) * (1.0f / 256.0f); ev = eb + (ec - eb) * (0.5f / 256.0f); }

  int sb = 0;
  for (int it = 0; it < 32; ++it) {
    float v0, v1, v2, v3, tn;
    v0 = ev * sph; tn = sph*crot + cph*srot; cph = cph*crot - sph*srot; sph = tn; ev += slope;
    v1 = ev * sph; tn = sph*crot + cph*srot; cph = cph*crot - sph*srot; sph = tn; ev += slope;
    v2 = ev * sph; tn = sph*crot + cph*srot; cph = cph*crot - sph*srot; sph = tn; ev += slope;
    v3 = ev * sph; tn = sph*crot + cph*srot; cph = cph*crot - sph*srot; sph = tn; ev += slope;
    float t0 = __shfl_xor(v0, 32);
    float t1 = __shfl_xor(v1, 32);
    float t2 = __shfl_xor(v2, 32);
    float t3 = __shfl_xor(v3, 32);
    bool b5 = (lane & 32) != 0;
    float w0 = b5 ? (v2 + t2) : (v0 + t0);
    float w1 = b5 ? (v3 + t3) : (v1 + t1);
    t0 = __shfl_xor(w0, 16);
    t1 = __shfl_xor(w1, 16);
    float xs = (lane & 16) ? (w1 + t1) : (w0 + t0);
    xs += __shfl_xor(xs, 8);
    xs += __shfl_xor(xs, 4);
    xs += __shfl_xor(xs, 2);
    xs += __shfl_xor(xs, 1);
    if ((lane & 15) == 0)
      part[w][sb + (lane >> 4)] = xs;
    sb += 4;
  }
  __syncthreads();

  // batch-mean of noise: 8 groups x 8 batches each
  {
    int j = tid & 127, grp = tid >> 7;
    const float* src = ws2f + (size_t)(grp * 8) * NSAMP + s0 + j;
    float acc = 0.0f;
    #pragma unroll
    for (int bb = 0; bb < 8; ++bb) acc += src[(size_t)bb * NSAMP];
    nse[grp][j] = acc;
  }
  __syncthreads();

  if (tid < 128) {
    float osc = 0.0f;
    #pragma unroll
    for (int ww = 0; ww < 16; ++ww) osc += part[ww][tid];
    float nz = 0.0f;
    #pragma unroll
    for (int g = 0; g < 8; ++g) nz += nse[g][tid];
    out[s0 + tid] = osc * (1.0f / 1024.0f) + nz * (1.0f / 64.0f);
  }
}

// ---------------------------------------------------------------------------
extern "C" void kernel_launch(void* const* d_in, const int* in_sizes, int n_in,
                              void* d_out, int out_size, void* d_ws, size_t ws_size,
                              hipStream_t stream) {
  const float* packed  = (const float*)d_in[0];
  const float* gumbel  = (const float*)d_in[1];
  const float* noise_u = (const float*)d_in[2];
  float* out = (float*)d_out;

  // ws layout: [r64 8KB][env 512KB][A 8MB][ws2 8MB]
  char* wsc = (char*)d_ws;
  double* r64_ws = (double*)wsc;
  float*  env_ws = (float*)(wsc + 8192);
  float2* A      = (float2*)(wsc + 8192 + 524288);
  float2* ws2    = (float2*)(wsc + 8192 + 524288 + (size_t)BATCH * MFFT * 8);

  k1_setup<<<BATCH, 128, 0, stream>>>(packed, gumbel, r64_ws, env_ws);
  kf1 <<<dim3(BATCH, 16), 256, 0, stream>>>(noise_u, A);
  kmid<<<dim3(BATCH, 16), 256, 0, stream>>>(packed, A);
  ki2 <<<dim3(BATCH, 16), 256, 0, stream>>>(packed, A, ws2);
  k3r <<<256, 1024, 0, stream>>>(r64_ws, env_ws, (const float*)ws2, out);
}

// Round 8
// 37.779 us; speedup vs baseline: 5.6411x; 1.4244x over previous
//
#include <hip/hip_runtime.h>
#include <math.h>

#define NSAMP   32768
#define NFRAMES 128
#define NHARM   16
#define BATCH   64
#define MFFT    16384          // complex FFT size (even/odd real pack), = 128*128
#define ZROW    137            // LDS row stride (float2) per 128-entry FFT row

static __device__ __forceinline__ float clampf(float x, float lo, float hi) {
  return fminf(fmaxf(x, lo), hi);
}
static __device__ __forceinline__ int zp(int fft, int p) {        // LDS swizzle
  return fft * ZROW + p + (p >> 4);
}
static __device__ __forceinline__ int brev7(int n) {
  return (int)(__brev((unsigned)n) >> 25);
}
static __device__ __forceinline__ float2 cmulf(float c, float s, float2 v) {
  return make_float2(c * v.x - s * v.y, c * v.y + s * v.x);
}
static __device__ __forceinline__ float2 f2add(float2 a, float2 b) {
  return make_float2(a.x + b.x, a.y + b.y);
}
static __device__ __forceinline__ float2 f2sub(float2 a, float2 b) {
  return make_float2(a.x - b.x, a.y - b.y);
}

static __device__ __forceinline__ void tw_init(float2* tws, int tid) {
  if (tid < 64) {
    float s, c;
    __sincosf(-(float)M_PI * (float)tid * (1.0f / 64.0f), &s, &c);
    tws[tid] = make_float2(c, s);
  }
}

// ---------------------------------------------------------------------------
// NT/32 FFTs of length 128 in LDS, NT threads, one radix-4 quad per thread
// per pass (3 radix-4 + 1 radix-2). DIT: bit-reversed input -> natural out.
// tws[j] = e^{-i pi j/64}; INV conjugates; w2b = (fwd) -i*w2a / (inv) +i*w2a.
// ---------------------------------------------------------------------------
template <int NT, bool INV>
static __device__ __forceinline__ void fft128_r4(float2* zs, const float2* tws, int tid) {
  constexpr int NF = NT / 32;
  int fft = tid >> 5, i = tid & 31;
  #pragma unroll
  for (int s = 0; s < 6; s += 2) {
    int half = 1 << s;
    int kk1 = i & (half - 1);
    int base = ((i & ~(half - 1)) << 2) | kk1;
    int p0 = zp(fft, base),            p1 = zp(fft, base + half);
    int p2 = zp(fft, base + 2 * half), p3 = zp(fft, base + 3 * half);
    float2 q0 = zs[p0], q1 = zs[p1], q2 = zs[p2], q3 = zs[p3];
    float2 t1 = tws[kk1 << (6 - s)], t2 = tws[kk1 << (5 - s)];
    float c1 = t1.x, s1 = INV ? -t1.y : t1.y;
    float c2 = t2.x, s2 = INV ? -t2.y : t2.y;
    float c2b = INV ? -s2 : s2, s2b = INV ? c2 : -c2;
    float2 t;
    t = cmulf(c1, s1, q1);   float2 A0 = f2add(q0, t), A1 = f2sub(q0, t);
    t = cmulf(c1, s1, q3);   float2 A2 = f2add(q2, t), A3 = f2sub(q2, t);
    t = cmulf(c2, s2, A2);   zs[p0] = f2add(A0, t); zs[p2] = f2sub(A0, t);
    t = cmulf(c2b, s2b, A3); zs[p1] = f2add(A1, t); zs[p3] = f2sub(A1, t);
    __syncthreads();
  }
  #pragma unroll
  for (int j = tid; j < NF * 64; j += NT) {        // stage 6, radix-2
    int f = j >> 6, kk = j & 63;
    float2 w = tws[kk];
    float cc = w.x, ss = INV ? -w.y : w.y;
    int a0 = zp(f, kk), a1 = zp(f, kk + 64);
    float2 a = zs[a0], bv = zs[a1];
    float2 t = cmulf(cc, ss, bv);
    zs[a0] = f2add(a, t); zs[a1] = f2sub(a, t);
  }
  __syncthreads();
}

// Inverse as DIF: natural input -> bit-reversed output. Stage 6 first, then
// fused pairs (5,4),(3,2),(1,0). Twiddles conjugated; w2b = +i*w2a.
template <int NT>
static __device__ __forceinline__ void fft128_r4_dif_inv(float2* zs, const float2* tws, int tid) {
  constexpr int NF = NT / 32;
  #pragma unroll
  for (int j = tid; j < NF * 64; j += NT) {        // stage 6, radix-2 DIF
    int f = j >> 6, kk = j & 63;
    float2 w = tws[kk];
    float cc = w.x, ss = -w.y;
    int a0 = zp(f, kk), a1 = zp(f, kk + 64);
    float2 u = zs[a0], v = zs[a1];
    zs[a0] = f2add(u, v);
    zs[a1] = cmulf(cc, ss, f2sub(u, v));
  }
  __syncthreads();
  int fft = tid >> 5, i = tid & 31;
  #pragma unroll
  for (int s = 4; s >= 0; s -= 2) {
    int half = 1 << s;
    int kk1 = i & (half - 1);
    int base = ((i & ~(half - 1)) << 2) | kk1;
    int p0 = zp(fft, base),            p1 = zp(fft, base + half);
    int p2 = zp(fft, base + 2 * half), p3 = zp(fft, base + 3 * half);
    float2 q0 = zs[p0], q1 = zs[p1], q2 = zs[p2], q3 = zs[p3];
    float2 t1 = tws[kk1 << (6 - s)], t2 = tws[kk1 << (5 - s)];
    float c1 = t1.x, s1 = -t1.y;
    float c2 = t2.x, s2 = -t2.y;
    float c2b = -s2, s2b = c2;                  // +i * (c2, s2)
    float2 B0 = f2add(q0, q2);
    float2 B2 = cmulf(c2, s2, f2sub(q0, q2));
    float2 B1 = f2add(q1, q3);
    float2 B3 = cmulf(c2b, s2b, f2sub(q1, q3));
    zs[p0] = f2add(B0, B1);
    zs[p1] = cmulf(c1, s1, f2sub(B0, B1));
    zs[p2] = f2add(B2, B3);
    zs[p3] = cmulf(c1, s1, f2sub(B2, B3));
    __syncthreads();
  }
}

static __device__ __forceinline__ float h_filter(int f, const float* nf_s) {
  float coords = ((float)f + 0.5f) * (1.0f / 256.0f) - 0.5f;
  coords = clampf(coords, 0.0f, 63.0f);
  int i0 = (int)coords;
  int i1 = (i0 < 63) ? (i0 + 1) : 63;
  float w = coords - (float)i0;
  return nf_s[i0] * (1.0f - w) + nf_s[i1] * w;
}

static __device__ __forceinline__ float amp_lerp(int s, const float* amp_s) {
  float coords = ((float)s + 0.5f) * (1.0f / 256.0f) - 0.5f;
  coords = clampf(coords, 0.0f, 127.0f);
  int i0 = (int)coords;
  int i1 = (i0 < 127) ? (i0 + 1) : 127;
  float w = coords - (float)i0;
  float v = amp_s[i0] * (1.0f - w) + amp_s[i1] * w;
  return clampf(v, 0.0f, 1.0f);
}

// ---------------------------------------------------------------------------
// k1 body (run as kf1's blockIdx.y==0 slice, 128 threads): gumbel argmax ->
// f0 -> per-harmonic radians (f64); 128-frame env scan.
// env layout: env_ws[frame*1024 + channel]
// ---------------------------------------------------------------------------
static __device__ void k1_body(
    const float* __restrict__ packed, const float* __restrict__ gumbel,
    double* __restrict__ r64_ws, float* __restrict__ env_ws, int b, int tid) {
  __shared__ double zv[128];
  __shared__ int    zi[128];
  __shared__ double f0_sh;
  const float* pk = packed + b * 480;

  double u = (double)gumbel[b * 128 + tid];
  double t = -log(u + 1e-10);
  double g = -log(t + 1e-10);
  zv[tid] = (double)pk[tid] + g;
  zi[tid] = tid;
  __syncthreads();
  for (int s = 64; s > 0; s >>= 1) {
    if (tid < s) {
      double a = zv[tid], c = zv[tid + s];
      int ia = zi[tid], ic = zi[tid + s];
      if (c > a || (c == a && ic < ia)) { zv[tid] = c; zi[tid] = ic; }
    }
    __syncthreads();
  }
  if (tid == 0) {
    int note = zi[0];
    double Fd  = 440.0 * exp2(((double)(note - 69)) / 12.0) / 11025.0;
    float  F32 = (float)Fd;                     // FREQS is f32 in the reference
    double f0  = (double)F32 * 11025.0;
    f0 = (40.0 / 11025.0) + f0 * (3000.0 / 11025.0 - 40.0 / 11025.0);
    f0_sh = f0;
  }
  __syncthreads();
  if (tid < NHARM) {
    int h = tid;
    int c = b * NHARM + h;
    const float PIF = 3.14159265358979323846f;  // float32(np.pi)
    double osc = f0_sh * (double)(h + 1);
    r64_ws[c] = (osc / 11025.0) * (double)PIF;
    float ha = pk[384 + h];
    float hd = 0.1f + pk[400 + h] * 0.9f;
    float cur = 0.0f;
    for (int tt = 0; tt < NFRAMES; ++tt) {
      float a = pk[256 + tt] * 2.0f - 1.0f;
      cur = clampf(cur + a * ha, 0.0f, 1.0f);
      env_ws[tt * 1024 + c] = cur;
      cur = cur * hd;
    }
  }
}

// ---------------------------------------------------------------------------
// kf1: column FFTs (length 128 over n1) + W_M^{n2 k1} twiddle; y==0 runs k1.
// grid (BATCH, 33) x 128; 4 columns per FFT WG.
// ---------------------------------------------------------------------------
__global__ __launch_bounds__(128, 4) void kf1(
    const float* __restrict__ noise_u, float2* __restrict__ A,
    const float* __restrict__ packed, const float* __restrict__ gumbel,
    double* __restrict__ r64_ws, float* __restrict__ env_ws) {
  int b = blockIdx.x, tid = threadIdx.x;
  if (blockIdx.y == 0) { k1_body(packed, gumbel, r64_ws, env_ws, b, tid); return; }
  int tile = blockIdx.y - 1;
  __shared__ float2 zs[4 * ZROW];
  __shared__ float2 tws[64];
  tw_init(tws, tid);
  const float2* nu2 = (const float2*)(noise_u + (size_t)b * NSAMP);
  #pragma unroll
  for (int it = 0; it < 4; ++it) {
    int e = it * 128 + tid;
    int n1 = e >> 2, n2l = e & 3;
    float2 xv = nu2[n1 * 128 + tile * 4 + n2l];
    zs[zp(n2l, brev7(n1))] = make_float2(xv.x * 2.0f - 1.0f, xv.y * 2.0f - 1.0f);
  }
  __syncthreads();
  fft128_r4<128, false>(zs, tws, tid);
  float2* Ab = A + (size_t)b * MFFT;
  #pragma unroll
  for (int it = 0; it < 4; ++it) {
    int e = it * 128 + tid;
    int k1 = e >> 2, n2l = e & 3;
    int n2 = tile * 4 + n2l;
    float2 v = zs[zp(n2l, k1)];
    float ang = -(2.0f * (float)M_PI / 16384.0f) * (float)(k1 * n2);
    float ss, cc; __sincosf(ang, &ss, &cc);
    Ab[k1 * 128 + n2] = make_float2(cc * v.x - ss * v.y, cc * v.y + ss * v.x);
  }
}

// ---------------------------------------------------------------------------
// kmid: fused row-FFT (fwd) -> Hermitian filter (in LDS) -> row-IFFT (DIF)
//       -> conj twiddle.  4 rows = 2 pair-groups per WG:
//       r in {0,1}: k1 = t*2+r;  r in {2,3}: k1 = pair(t*2+r-2), pair(0)=64.
// grid (BATCH, 32) x 128
// ---------------------------------------------------------------------------
__global__ __launch_bounds__(128, 4) void kmid(
    const float* __restrict__ packed, float2* __restrict__ A) {
  __shared__ float2 zs[4 * ZROW];
  __shared__ float2 tws[64];
  __shared__ float  nf_s[64];
  __shared__ int    rowk1[4];
  int b = blockIdx.x, t = blockIdx.y, tid = threadIdx.x;
  tw_init(tws, tid);
  if (tid >= 64 && tid < 128) nf_s[tid - 64] = packed[b * 480 + 416 + (tid - 64)];
  if (tid < 4) {
    int s = tid & 1;
    int m = t * 2 + s;
    rowk1[tid] = (tid < 2) ? m : ((m == 0) ? 64 : 128 - m);
  }
  __syncthreads();
  float2* Ab = A + (size_t)b * MFFT;

  // load 4 rows, bitrev over k2
  #pragma unroll
  for (int it = 0; it < 4; ++it) {
    int e = it * 128 + tid;
    int r = e >> 7, n2 = e & 127;
    zs[zp(r, brev7(n2))] = Ab[rowk1[r] * 128 + n2];
  }
  __syncthreads();
  fft128_r4<128, false>(zs, tws, tid);   // zs[zp(r,k2)] = Z[rowk1[r] + 128*k2]

  // Hermitian unpack * H/M * repack; pair (k1,k2) <-> (128-k1, 127-k2),
  // each unordered pair owned by exactly one task (k2 <= 63).
  const float hsc = 1.0f / 16384.0f;
  #pragma unroll
  for (int it = 0; it < 2; ++it) {
    int task = it * 128 + tid;      // 256 tasks: (local row r, k2 in 0..63)
    int r  = task >> 6;
    int k2 = task & 63;
    int k1 = rowk1[r];
    int f = k1 + (k2 << 7);
    if (f == 0) {                   // DC and f=8192 specials (WG t=0 only)
      float2 Z0 = zs[zp(0, 0)];
      float X0 = Z0.x + Z0.y;
      float Y0 = X0 * (h_filter(0, nf_s) * hsc);
      zs[zp(0, 0)] = make_float2(0.5f * Y0, 0.5f * Y0);   // H[M]=0 -> YM=0
      float Hm = h_filter(8192, nf_s) * hsc;
      float2 Zm = zs[zp(0, 64)];
      zs[zp(0, 64)] = make_float2(Zm.x * Hm, Zm.y * Hm);
    } else {
      int g = 16384 - f;
      int k1g = g & 127;
      int pr = (k1g == k1) ? r : ((r < 2) ? r + 2 : r - 2);
      int k2p = g >> 7;
      float2 Zf = zs[zp(r, k2)], Zg = zs[zp(pr, k2p)];
      float Ax = 0.5f * (Zf.x + Zg.x), Ay = 0.5f * (Zf.y - Zg.y);
      float Bx = 0.5f * (Zf.x - Zg.x), By = 0.5f * (Zf.y + Zg.y);
      float ang = (-(float)M_PI / (float)MFFT) * (float)f;
      float ss, cc; __sincosf(ang, &ss, &cc);
      float WBx = cc * Bx - ss * By, WBy = cc * By + ss * Bx;
      float Hf = h_filter(f, nf_s) * hsc;
      float Hg = h_filter(g, nf_s) * hsc;
      float Yfx = (Ax + WBy) * Hf, Yfy = (Ay - WBx) * Hf;
      float Ygx = (Ax - WBy) * Hg, Ygy = (-Ay - WBx) * Hg;
      float A2x = 0.5f * (Yfx + Ygx), A2y = 0.5f * (Yfy - Ygy);
      float B2x = 0.5f * (Yfx - Ygx), B2y = 0.5f * (Yfy + Ygy);
      float CBx = cc * B2x + ss * B2y;
      float CBy = cc * B2y - ss * B2x;
      zs[zp(r, k2)]   = make_float2(A2x - CBy, A2y + CBx);
      float DBx = cc * B2x + ss * B2y;
      float DBy = ss * B2x - cc * B2y;
      zs[zp(pr, k2p)] = make_float2(A2x - DBy, -A2y + DBx);
    }
  }
  __syncthreads();

  fft128_r4_dif_inv<128>(zs, tws, tid);  // natural -> bitrev

  // store, un-bitrev + conj twiddle
  #pragma unroll
  for (int it = 0; it < 4; ++it) {
    int e = it * 128 + tid;
    int r = e >> 7, n2 = e & 127;
    int k1 = rowk1[r];
    float2 v = zs[zp(r, brev7(n2))];
    float ang = (2.0f * (float)M_PI / 16384.0f) * (float)(k1 * n2);
    float ss, cc; __sincosf(ang, &ss, &cc);
    Ab[k1 * 128 + n2] = make_float2(cc * v.x - ss * v.y, cc * v.y + ss * v.x);
  }
}

// ---------------------------------------------------------------------------
// ki2: column inverse FFTs (over k1) + amp*clip -> ws2 (per-batch samples).
// grid (BATCH, 32) x 128; 4 columns per WG.
// ---------------------------------------------------------------------------
__global__ __launch_bounds__(128, 4) void ki2(
    const float* __restrict__ packed, const float2* __restrict__ A,
    float2* __restrict__ ws2) {
  __shared__ float2 zs[4 * ZROW];
  __shared__ float2 tws[64];
  __shared__ float amp_s[128];
  int b = blockIdx.x, tile = blockIdx.y, tid = threadIdx.x;
  tw_init(tws, tid);
  amp_s[tid] = packed[b * 480 + 256 + tid] * 2.0f - 1.0f;
  const float2* Ab = A + (size_t)b * MFFT;
  #pragma unroll
  for (int it = 0; it < 4; ++it) {
    int e = it * 128 + tid;
    int k1 = e >> 2, n2l = e & 3;
    zs[zp(n2l, brev7(k1))] = Ab[k1 * 128 + tile * 4 + n2l];
  }
  __syncthreads();
  fft128_r4<128, true>(zs, tws, tid);
  float2* W2 = ws2 + (size_t)b * MFFT;
  #pragma unroll
  for (int it = 0; it < 4; ++it) {
    int e = it * 128 + tid;
    int n1 = e >> 2, n2l = e & 3;
    int n2 = tile * 4 + n2l;
    int n = n1 * 128 + n2;
    float2 v = zs[zp(n2l, n1)];
    v.x *= amp_lerp(2 * n,     amp_s);
    v.y *= amp_lerp(2 * n + 1, amp_s);
    W2[n] = v;
  }
}

// ---------------------------------------------------------------------------
// k3r: oscillator bank via Chebyshev harmonic recurrence + batch-mean of
// noise. 256 WGs x 1024 thr; thread = (batch=lane, 8-sample group=wave).
// sin((i+1)phi) = 2cos(phi) sin(i phi) - sin((i-1) phi); wave's 64 lanes are
// the 64 batches, so one butterfly reduce finishes each sample.
// ---------------------------------------------------------------------------
__global__ __launch_bounds__(1024) void k3r(
    const double* __restrict__ r64_ws, const float* __restrict__ env_ws,
    const float* __restrict__ ws2f, float* __restrict__ out) {
  __shared__ float oscs[128];
  __shared__ float nse[8][128];
  const double TWO_PI     = 6.283185307179586476925286766559;
  const double INV_TWO_PI = 0.15915494309189533576888376337251;
  int tid = threadIdx.x;
  int lane = tid & 63;               // batch
  int wv = tid >> 6;                 // sample group (0..15), 8 samples each
  int k = blockIdx.x;                // 128-sample chunk
  int s0 = k * 128;
  int K = k >> 1, half = k & 1;

  double r0 = r64_ws[lane * 16];     // fundamental step angle (f64)
  double rr = r0 - rint(r0 * INV_TWO_PI) * TWO_PI;
  double x0 = (double)(s0 + wv * 8 + 1) * r0;
  double ph = x0 - rint(x0 * INV_TWO_PI) * TWO_PI;
  float s1, c1, srot, crot;
  __sincosf((float)ph, &s1, &c1);
  __sincosf((float)rr, &srot, &crot);

  int km1 = (K > 0) ? (K - 1) : 0;
  int kp1 = (K < 127) ? (K + 1) : 127;
  int fA = half ? K : km1;
  int fB = half ? kp1 : K;
  const float4* eA = (const float4*)(env_ws + fA * 1024 + lane * 16);
  const float4* eB = (const float4*)(env_ws + fB * 1024 + lane * 16);
  float ev[16], sl[16];
  float basew = (half ? 0.5f : 128.5f) + (float)(wv * 8);
  #pragma unroll
  for (int q = 0; q < 4; ++q) {
    float4 a = eA[q], bb = eB[q];
    float d;
    d = (bb.x - a.x) * (1.0f / 256.0f); sl[q*4+0] = d; ev[q*4+0] = a.x + d * basew;
    d = (bb.y - a.y) * (1.0f / 256.0f); sl[q*4+1] = d; ev[q*4+1] = a.y + d * basew;
    d = (bb.z - a.z) * (1.0f / 256.0f); sl[q*4+2] = d; ev[q*4+2] = a.z + d * basew;
    d = (bb.w - a.w) * (1.0f / 256.0f); sl[q*4+3] = d; ev[q*4+3] = a.w + d * basew;
  }

  #pragma unroll
  for (int j = 0; j < 8; ++j) {
    float twoC = c1 + c1;
    float sm1 = 0.0f, sc = s1;
    float acc = ev[0] * sc; ev[0] += sl[0];
    #pragma unroll
    for (int i = 1; i < 16; ++i) {
      float sn = fmaf(twoC, sc, -sm1);
      sm1 = sc; sc = sn;
      acc = fmaf(ev[i], sn, acc);
      ev[i] += sl[i];
    }
    acc += __shfl_xor(acc, 32);
    acc += __shfl_xor(acc, 16);
    acc += __shfl_xor(acc, 8);
    acc += __shfl_xor(acc, 4);
    acc += __shfl_xor(acc, 2);
    acc += __shfl_xor(acc, 1);
    if (lane == 0) oscs[wv * 8 + j] = acc;
    float tn = fmaf(s1, crot, c1 * srot);      // uses old s1,c1
    c1 = fmaf(c1, crot, -(s1 * srot));
    s1 = tn;
  }
  __syncthreads();

  // batch-mean of noise: 8 groups x 8 batches each, coalesced rows
  {
    int j = tid & 127, grp = tid >> 7;
    const float* src = ws2f + (size_t)(grp * 8) * NSAMP + s0 + j;
    float acc = 0.0f;
    #pragma unroll
    for (int bb = 0; bb < 8; ++bb) acc += src[(size_t)bb * NSAMP];
    nse[grp][j] = acc;
  }
  __syncthreads();

  if (tid < 128) {
    float nz = 0.0f;
    #pragma unroll
    for (int g = 0; g < 8; ++g) nz += nse[g][tid];
    out[s0 + tid] = oscs[tid] * (1.0f / 1024.0f) + nz * (1.0f / 64.0f);
  }
}

// ---------------------------------------------------------------------------
extern "C" void kernel_launch(void* const* d_in, const int* in_sizes, int n_in,
                              void* d_out, int out_size, void* d_ws, size_t ws_size,
                              hipStream_t stream) {
  const float* packed  = (const float*)d_in[0];
  const float* gumbel  = (const float*)d_in[1];
  const float* noise_u = (const float*)d_in[2];
  float* out = (float*)d_out;

  // ws layout: [r64 8KB][env 512KB][A 8MB][ws2 8MB]
  char* wsc = (char*)d_ws;
  double* r64_ws = (double*)wsc;
  float*  env_ws = (float*)(wsc + 8192);
  float2* A      = (float2*)(wsc + 8192 + 524288);
  float2* ws2    = (float2*)(wsc + 8192 + 524288 + (size_t)BATCH * MFFT * 8);

  kf1 <<<dim3(BATCH, 33), 128, 0, stream>>>(noise_u, A, packed, gumbel, r64_ws, env_ws);
  kmid<<<dim3(BATCH, 32), 128, 0, stream>>>(packed, A);
  ki2 <<<dim3(BATCH, 32), 128, 0, stream>>>(packed, A, ws2);
  k3r <<<256, 1024, 0, stream>>>(r64_ws, env_ws, (const float*)ws2, out);
}